// Round 5
// baseline (3892.942 us; speedup 1.0000x reference)
//
#include <hip/hip_runtime.h>
#include <math.h>

#define B_SZ 64
#define T_IN 80
#define H_SZ 256
#define V_SZ 6144
#define L_DEC 30
#define SYMBASE (B_SZ * L_DEC * V_SZ)

typedef unsigned long long u64;

__device__ __forceinline__ float sigf(float x) { return 1.f / (1.f + expf(-x)); }

// monotone float->uint pack, first-index tie-break in low bits
__device__ __forceinline__ u64 packmax(float v, int idx) {
    unsigned u = __float_as_uint(v);
    u = (u & 0x80000000u) ? ~u : (u | 0x80000000u);
    return ((u64)u << 32) | (unsigned)(0x7FFFFFFF - idx);
}

__device__ __forceinline__ void fma44(float4& a0, float4& a1, float s, float4 w0, float4 w1) {
    a0.x = fmaf(s, w0.x, a0.x); a0.y = fmaf(s, w0.y, a0.y);
    a0.z = fmaf(s, w0.z, a0.z); a0.w = fmaf(s, w0.w, a0.w);
    a1.x = fmaf(s, w1.x, a1.x); a1.y = fmaf(s, w1.y, a1.y);
    a1.z = fmaf(s, w1.z, a1.z); a1.w = fmaf(s, w1.w, a1.w);
}

// ---------------- transpose: in [R][C] -> out [C][R] ----------------
__global__ __launch_bounds__(256) void ktranspose(const float* __restrict__ in,
                                                  float* __restrict__ out,
                                                  int R, int C) {
    __shared__ float tile[32][33];
    int c0 = blockIdx.x * 32, r0 = blockIdx.y * 32;
    int tx = threadIdx.x, ty = threadIdx.y;  // block (32,8)
    for (int i = ty; i < 32; i += 8) {
        int r = r0 + i, c = c0 + tx;
        tile[i][tx] = (r < R && c < C) ? in[(size_t)r * C + c] : 0.f;
    }
    __syncthreads();
    for (int i = ty; i < 32; i += 8) {
        int c = c0 + i, r = r0 + tx;
        if (c < C && r < R) out[(size_t)c * R + r] = tile[tx][i];
    }
}

// ---------------- bias sums ----------------
__global__ void biasum(const float* a1, const float* b1, const float* a2, const float* b2,
                       float* o1, float* o2) {
    int i = blockIdx.x * 256 + threadIdx.x;
    if (i < 1024) { o1[i] = a1[i] + b1[i]; o2[i] = a2[i] + b2[i]; }
}

// ---------------- pack W[1024][256] -> Wp[k/4][1024 g][4 kr] (k-major, lane-coalesced) ----
__global__ __launch_bounds__(256) void packWk(const float* __restrict__ W,
                                              float* __restrict__ Wp) {
    int idx = blockIdx.x * 256 + threadIdx.x;   // grid 1024 -> 262144
    int g = idx >> 8, k = idx & 255;
    Wp[(size_t)(k >> 2) * 4096 + g * 4 + (k & 3)] = W[idx];
}

// ---------------- tiled fp32 GEMM: C[M][N] = A[M][K] * W[N][K]^T + bias[N] ----
// BM=64, BN=128, BK=16, 256 threads, 4x8 micro-tile
__global__ __launch_bounds__(256) void gemm_rr(const float* __restrict__ A,
                                               const float* __restrict__ W,
                                               const float* __restrict__ bias,
                                               float* __restrict__ C,
                                               int M, int N, int K) {
    __shared__ __align__(16) float As[16][68];
    __shared__ __align__(16) float Bs[16][132];
    const int tid = threadIdx.x;
    const int tx = tid & 15, ty = tid >> 4;
    const int m0 = blockIdx.y * 64, n0 = blockIdx.x * 128;
    const int a_m = tid >> 2, a_k = (tid & 3) * 4;
    const int b_n = tid >> 1, b_k = (tid & 1) * 8;

    float acc[4][8];
#pragma unroll
    for (int r = 0; r < 4; ++r)
#pragma unroll
        for (int c = 0; c < 8; ++c) acc[r][c] = 0.f;

    for (int k0 = 0; k0 < K; k0 += 16) {
        float4 av  = *(const float4*)(A + (size_t)(m0 + a_m) * K + k0 + a_k);
        float4 bv0 = *(const float4*)(W + (size_t)(n0 + b_n) * K + k0 + b_k);
        float4 bv1 = *(const float4*)(W + (size_t)(n0 + b_n) * K + k0 + b_k + 4);
        __syncthreads();
        As[a_k + 0][a_m] = av.x; As[a_k + 1][a_m] = av.y;
        As[a_k + 2][a_m] = av.z; As[a_k + 3][a_m] = av.w;
        Bs[b_k + 0][b_n] = bv0.x; Bs[b_k + 1][b_n] = bv0.y;
        Bs[b_k + 2][b_n] = bv0.z; Bs[b_k + 3][b_n] = bv0.w;
        Bs[b_k + 4][b_n] = bv1.x; Bs[b_k + 5][b_n] = bv1.y;
        Bs[b_k + 6][b_n] = bv1.z; Bs[b_k + 7][b_n] = bv1.w;
        __syncthreads();
#pragma unroll
        for (int kk = 0; kk < 16; ++kk) {
            float4 a0 = *(const float4*)&As[kk][ty * 4];
            float4 b0 = *(const float4*)&Bs[kk][tx * 8];
            float4 b1 = *(const float4*)&Bs[kk][tx * 8 + 4];
            float ar[4] = {a0.x, a0.y, a0.z, a0.w};
            float br[8] = {b0.x, b0.y, b0.z, b0.w, b1.x, b1.y, b1.z, b1.w};
#pragma unroll
            for (int r = 0; r < 4; ++r)
#pragma unroll
                for (int c = 0; c < 8; ++c)
                    acc[r][c] = fmaf(ar[r], br[c], acc[r][c]);
        }
    }
#pragma unroll
    for (int r = 0; r < 4; ++r) {
        float* Crow = C + (size_t)(m0 + ty * 4 + r) * N + n0 + tx * 8;
#pragma unroll
        for (int c = 0; c < 8; ++c)
            Crow[c] = acc[r][c] + bias[n0 + tx * 8 + c];
    }
}

// ---------------- step-0 outputs: dec_o0 broadcast + SOS symbols ----------------
__global__ __launch_bounds__(256) void dec0(const float* __restrict__ embed,
                                            const float* __restrict__ Wout,
                                            const float* __restrict__ bout,
                                            float* __restrict__ out) {
    __shared__ float es[256];
    int tid = threadIdx.x;
    int v = blockIdx.x * 256 + tid;
    es[tid] = embed[256 + tid];  // row SOS=1
    __syncthreads();
    float a = 0.f, a2 = 0.f;
    const float* wr = Wout + (size_t)v * 256;
    for (int k = 0; k < 256; k += 8) {
        float4 w0 = *(const float4*)(wr + k);
        float4 w1 = *(const float4*)(wr + k + 4);
        a  = fmaf(es[k+0],w0.x,fmaf(es[k+1],w0.y,fmaf(es[k+2],w0.z,fmaf(es[k+3],w0.w,a))));
        a2 = fmaf(es[k+4],w1.x,fmaf(es[k+5],w1.y,fmaf(es[k+6],w1.z,fmaf(es[k+7],w1.w,a2))));
    }
    float lg = a + a2 + bout[v];
    for (int b = 0; b < B_SZ; ++b) out[(size_t)b * L_DEC * V_SZ + v] = lg;
    if (blockIdx.x == 0 && tid < B_SZ) out[SYMBASE + tid * L_DEC] = 1.0f;
}

// ---------------- fused encoder+decoder: one block per batch, ZERO grid sync ----------
// 64 blocks x 1024 threads. h,c live in LDS across all 109 steps.
// Encoder: thread g computes gate g (dot over k via packed [kq][g] float4 weights).
// Decoder: same + x-part from embed[sym]; logits: threads 0..767 x 8 V-cols each.
__global__ __launch_bounds__(1024) void seq_fused(
    const float4* __restrict__ Wp1,    // Whh1 packed [64 kq][1024 g] float4
    const float4* __restrict__ Wp2h,   // Whh2 packed
    const float4* __restrict__ Wp2x,   // Wih2 packed
    const float*  __restrict__ X1,     // [5120][1024] input@Wih1^T + bias
    const float*  __restrict__ bs2,    // b_ih2 + b_hh2 [1024]
    const float4* __restrict__ embed4, // [V][64] float4
    const float4* __restrict__ WoT4,   // WoT [256 k][1536] float4 (=[256][6144] floats)
    const float4* __restrict__ bout4,  // [1536] float4
    float* __restrict__ out) {
    __shared__ __align__(16) float hs[256];
    __shared__ float cs[256];
    __shared__ float gbuf[1024];
    __shared__ __align__(16) float es[256];
    __shared__ u64 red[16];
    __shared__ int ssym;
    const int tid = threadIdx.x;
    const int b = blockIdx.x;
    if (tid < 256) { hs[tid] = 0.f; cs[tid] = 0.f; }
    if (tid == 0) ssym = 1;  // SOS
    __syncthreads();
    const float4* hq = (const float4*)hs;
    const float4* eq = (const float4*)es;

    // ---- encoder: 80 steps ----
    for (int t = 0; t < T_IN; ++t) {
        float acc = X1[((size_t)(b * T_IN + t) << 10) + tid];
        const float4* wp = Wp1 + tid;
#pragma unroll 8
        for (int kq = 0; kq < 64; ++kq) {
            float4 w = wp[kq << 10];
            float4 h4 = hq[kq];
            acc = fmaf(h4.x, w.x, fmaf(h4.y, w.y, fmaf(h4.z, w.z, fmaf(h4.w, w.w, acc))));
        }
        gbuf[tid] = acc;
        __syncthreads();
        if (tid < 256) {
            float cn = sigf(gbuf[256 + tid]) * cs[tid] + sigf(gbuf[tid]) * tanhf(gbuf[512 + tid]);
            cs[tid] = cn;
            hs[tid] = sigf(gbuf[768 + tid]) * tanhf(cn);
        }
        __syncthreads();
    }

    // ---- decoder: 29 steps ----
    for (int l = 0; l < L_DEC - 1; ++l) {
        if (tid < 64) ((float4*)es)[tid] = embed4[(size_t)ssym * 64 + tid];
        __syncthreads();
        // LSTM2 gates: thread g = dot(Whh2[g], h) + dot(Wih2[g], emb) + bias
        {
            float acc = bs2[tid];
            const float4* wph = Wp2h + tid;
            const float4* wpx = Wp2x + tid;
#pragma unroll 4
            for (int kq = 0; kq < 64; ++kq) {
                float4 wh = wph[kq << 10];
                float4 h4 = hq[kq];
                float4 wx = wpx[kq << 10];
                float4 e4 = eq[kq];
                acc = fmaf(h4.x, wh.x, fmaf(h4.y, wh.y, fmaf(h4.z, wh.z, fmaf(h4.w, wh.w, acc))));
                acc = fmaf(e4.x, wx.x, fmaf(e4.y, wx.y, fmaf(e4.z, wx.z, fmaf(e4.w, wx.w, acc))));
            }
            gbuf[tid] = acc;
        }
        __syncthreads();
        if (tid < 256) {
            float cn = sigf(gbuf[256 + tid]) * cs[tid] + sigf(gbuf[tid]) * tanhf(gbuf[512 + tid]);
            cs[tid] = cn;
            hs[tid] = sigf(gbuf[768 + tid]) * tanhf(cn);
        }
        __syncthreads();

        // logits GEMV: threads 0..767 own cols [8*tid, 8*tid+8)
        u64 mybest = 0ull;
        if (tid < 768) {
            float4 a0 = {0.f, 0.f, 0.f, 0.f}, a1 = {0.f, 0.f, 0.f, 0.f};
#pragma unroll 4
            for (int kq = 0; kq < 64; ++kq) {
                float4 h4 = hq[kq];
                const float4* w = WoT4 + (size_t)(kq * 4) * 1536 + tid * 2;
                fma44(a0, a1, h4.x, w[0],    w[1]);
                fma44(a0, a1, h4.y, w[1536], w[1537]);
                fma44(a0, a1, h4.z, w[3072], w[3073]);
                fma44(a0, a1, h4.w, w[4608], w[4609]);
            }
            float4 b0 = bout4[tid * 2], b1 = bout4[tid * 2 + 1];
            a0.x += b0.x; a0.y += b0.y; a0.z += b0.z; a0.w += b0.w;
            a1.x += b1.x; a1.y += b1.y; a1.z += b1.z; a1.w += b1.w;
            float4* orow = (float4*)(out + (size_t)(b * L_DEC + l + 1) * V_SZ) + tid * 2;
            orow[0] = a0; orow[1] = a1;
            const int v0 = tid * 8;
            u64 p;
            p = packmax(a0.x, v0 + 0); if (p > mybest) mybest = p;
            p = packmax(a0.y, v0 + 1); if (p > mybest) mybest = p;
            p = packmax(a0.z, v0 + 2); if (p > mybest) mybest = p;
            p = packmax(a0.w, v0 + 3); if (p > mybest) mybest = p;
            p = packmax(a1.x, v0 + 4); if (p > mybest) mybest = p;
            p = packmax(a1.y, v0 + 5); if (p > mybest) mybest = p;
            p = packmax(a1.z, v0 + 6); if (p > mybest) mybest = p;
            p = packmax(a1.w, v0 + 7); if (p > mybest) mybest = p;
        }
        // wave reduce (all waves execute; idle waves contribute 0)
        {
            u64 m = mybest;
#pragma unroll
            for (int off = 32; off; off >>= 1) {
                u64 o = (u64)__shfl_down((long long)m, off);
                if (o > m) m = o;
            }
            if ((tid & 63) == 0) red[tid >> 6] = m;
        }
        __syncthreads();
        if (tid == 0) {
            u64 m = red[0];
#pragma unroll
            for (int j = 1; j < 16; ++j) if (red[j] > m) m = red[j];
            int idx = (int)(0x7FFFFFFFu - (unsigned)(m & 0xFFFFFFFFu));
            ssym = idx;
            out[SYMBASE + b * L_DEC + l + 1] = (float)idx;
        }
        __syncthreads();
    }
}

extern "C" void kernel_launch(void* const* d_in, const int* in_sizes, int n_in,
                              void* d_out, int out_size, void* d_ws, size_t ws_size,
                              hipStream_t stream) {
    const float* input = (const float*)d_in[0];
    // d_in[1] target_lengths: all == L_DEC, unused
    const float* embed = (const float*)d_in[2];
    const float* W_out = (const float*)d_in[3];
    const float* b_out = (const float*)d_in[4];
    const float* W_ih1 = (const float*)d_in[5];
    const float* W_hh1 = (const float*)d_in[6];
    const float* b_ih1 = (const float*)d_in[7];
    const float* b_hh1 = (const float*)d_in[8];
    const float* W_ih2 = (const float*)d_in[9];
    const float* W_hh2 = (const float*)d_in[10];
    const float* b_ih2 = (const float*)d_in[11];
    const float* b_hh2 = (const float*)d_in[12];
    float* out = (float*)d_out;

    float* ws = (float*)d_ws;
    float* X1   = ws; ws += 5120 * 1024;    // input GEMM result (bias folded)
    float* Wp1  = ws; ws += 256 * 1024;     // Whh1 k-major packed
    float* Wp2h = ws; ws += 256 * 1024;     // Whh2 packed
    float* Wp2x = ws; ws += 256 * 1024;     // Wih2 packed
    float* WoT  = ws; ws += 256 * 6144;     // W_out transposed [256][6144]
    float* bs1  = ws; ws += 1024;
    float* bs2  = ws; ws += 1024;
    if (ws_size < (size_t)((float*)ws - (float*)d_ws) * 4) return;

    biasum<<<4, 256, 0, stream>>>(b_ih1, b_hh1, b_ih2, b_hh2, bs1, bs2);
    packWk<<<1024, 256, 0, stream>>>(W_hh1, Wp1);
    packWk<<<1024, 256, 0, stream>>>(W_hh2, Wp2h);
    packWk<<<1024, 256, 0, stream>>>(W_ih2, Wp2x);
    ktranspose<<<dim3(8, 192), dim3(32, 8), 0, stream>>>(W_out, WoT, V_SZ, H_SZ);
    // X1 = input @ W_ih1^T + (b_ih1+b_hh1) : [5120 x 1024], K=4096
    gemm_rr<<<dim3(8, 80), 256, 0, stream>>>(input, W_ih1, bs1, X1, 5120, 1024, 4096);
    dec0<<<24, 256, 0, stream>>>(embed, W_out, b_out, out);
    seq_fused<<<B_SZ, 1024, 0, stream>>>((const float4*)Wp1, (const float4*)Wp2h,
                                         (const float4*)Wp2x, X1, bs2,
                                         (const float4*)embed, (const float4*)WoT,
                                         (const float4*)b_out, out);
}

// Round 6
// 2783.096 us; speedup vs baseline: 1.3988x; 1.3988x over previous
//
#include <hip/hip_runtime.h>
#include <math.h>

#define B_SZ 64
#define T_IN 80
#define H_SZ 256
#define V_SZ 6144
#define L_DEC 30
#define SYMBASE (B_SZ * L_DEC * V_SZ)
#define CH 66560            // X1 t-chunk stride in floats (64*1024 + 1024 guard)
#define HSTRIDE 17408       // h rotating buffer stride floats (16384 + 1024 guard)
#define PSTRIDE 8704        // parts rotating stride u64 (8192 + 512 guard)
#define NDB 128             // decoder blocks
#define GX1 640             // X1 gemm blocks (8 n x 80 t)
#define GE2 768             // E2 gemm blocks (8 n x 96 m)
#define GD0 24              // dec0 blocks
#define GENC 64             // encoder blocks
#define NB1 (GX1 + GE2 + GD0 + GENC)

typedef unsigned long long u64;

__device__ __forceinline__ float sigf(float x) { return 1.f / (1.f + expf(-x)); }

// monotone float->uint pack, first-index tie-break in low bits (never 0)
__device__ __forceinline__ u64 packmax(float v, int idx) {
    unsigned u = __float_as_uint(v);
    u = (u & 0x80000000u) ? ~u : (u | 0x80000000u);
    return ((u64)u << 32) | (unsigned)(0x7FFFFFFF - idx);
}
__device__ __forceinline__ u64 pk2(float lo, float hi) {
    return (u64)__float_as_uint(lo) | ((u64)__float_as_uint(hi) << 32);
}

// ---------------- bias sums ----------------
__global__ void biasum(const float* a1, const float* b1, const float* a2, const float* b2,
                       float* o1, float* o2) {
    int i = blockIdx.x * 256 + threadIdx.x;
    if (i < 1024) { o1[i] = a1[i] + b1[i]; o2[i] = a2[i] + b2[i]; }
}

// ---------------- init: zero flags + chunk counters ----------------
__global__ void init0(int* flagA, int* flagB, unsigned* cnt) {
    int i = blockIdx.x * 256 + threadIdx.x;
    int n = 29 * NDB * 32;
    for (int j = i; j < n; j += 256 * 256) { flagA[j] = 0; flagB[j] = 0; }
    if (i < 80 * 32) cnt[i] = 0u;
}

// ---------------- pack Whh1 [1024][256] -> [64 kq][1024 g] float4 ----------------
__global__ __launch_bounds__(256) void packWk(const float* __restrict__ W,
                                              float* __restrict__ Wp) {
    int idx = blockIdx.x * 256 + threadIdx.x;    // 262144
    int g = idx >> 8, k = idx & 255;
    Wp[(size_t)(k >> 2) * 4096 + g * 4 + (k & 3)] = W[idx];
}

// ---------------- shared gemm body: C[64][N=1024 tile] = A*W^T + bias ----------------
// BM=64, BN=128, BK=16, 256 threads, 4x8 micro-tile
__device__ __forceinline__ void gemm_body(
    const float* __restrict__ A, size_t astride, size_t aoff,
    const float* __restrict__ W, const float* __restrict__ bias,
    float* __restrict__ Cbase, int atomicC, int n0, int K, float* smem) {
    float* As = smem;              // [16][68]
    float* Bs = smem + 16 * 68;    // [16][132]
    const int tid = threadIdx.x;
    const int tx = tid & 15, ty = tid >> 4;
    const int a_m = tid >> 2, a_k = (tid & 3) * 4;
    const int b_n = tid >> 1, b_k = (tid & 1) * 8;

    float acc[4][8];
#pragma unroll
    for (int r = 0; r < 4; ++r)
#pragma unroll
        for (int c = 0; c < 8; ++c) acc[r][c] = 0.f;

    for (int k0 = 0; k0 < K; k0 += 16) {
        float4 av  = *(const float4*)(A + (size_t)a_m * astride + aoff + k0 + a_k);
        float4 bv0 = *(const float4*)(W + (size_t)(n0 + b_n) * K + k0 + b_k);
        float4 bv1 = *(const float4*)(W + (size_t)(n0 + b_n) * K + k0 + b_k + 4);
        __syncthreads();
        As[(a_k + 0) * 68 + a_m] = av.x; As[(a_k + 1) * 68 + a_m] = av.y;
        As[(a_k + 2) * 68 + a_m] = av.z; As[(a_k + 3) * 68 + a_m] = av.w;
        Bs[(b_k + 0) * 132 + b_n] = bv0.x; Bs[(b_k + 1) * 132 + b_n] = bv0.y;
        Bs[(b_k + 2) * 132 + b_n] = bv0.z; Bs[(b_k + 3) * 132 + b_n] = bv0.w;
        Bs[(b_k + 4) * 132 + b_n] = bv1.x; Bs[(b_k + 5) * 132 + b_n] = bv1.y;
        Bs[(b_k + 6) * 132 + b_n] = bv1.z; Bs[(b_k + 7) * 132 + b_n] = bv1.w;
        __syncthreads();
#pragma unroll
        for (int kk = 0; kk < 16; ++kk) {
            float4 a0 = *(const float4*)&As[kk * 68 + ty * 4];
            float4 b0 = *(const float4*)&Bs[kk * 132 + tx * 8];
            float4 b1 = *(const float4*)&Bs[kk * 132 + tx * 8 + 4];
            float ar[4] = {a0.x, a0.y, a0.z, a0.w};
            float br[8] = {b0.x, b0.y, b0.z, b0.w, b1.x, b1.y, b1.z, b1.w};
#pragma unroll
            for (int r = 0; r < 4; ++r)
#pragma unroll
                for (int c = 0; c < 8; ++c)
                    acc[r][c] = fmaf(ar[r], br[c], acc[r][c]);
        }
    }
#pragma unroll
    for (int r = 0; r < 4; ++r) {
        int row = ty * 4 + r, col = n0 + tx * 8;
        float* Crow = Cbase + (size_t)row * 1024 + col;
        if (atomicC) {
#pragma unroll
            for (int c = 0; c < 8; c += 2) {
                u64 v = pk2(acc[r][c] + bias[col + c], acc[r][c + 1] + bias[col + c + 1]);
                __hip_atomic_store((u64*)(Crow + c), v,
                                   __ATOMIC_RELAXED, __HIP_MEMORY_SCOPE_AGENT);
            }
        } else {
#pragma unroll
            for (int c = 0; c < 8; ++c) Crow[c] = acc[r][c] + bias[col + c];
        }
    }
}

// ---------------- mega1: X1 gemm ∥ E2 gemm ∥ dec0 ∥ encoder (polls X1 chunks) --------
__global__ __launch_bounds__(256) void mega1(
    const float* __restrict__ input, const float* __restrict__ W_ih1,
    const float* __restrict__ bs1,
    const float* __restrict__ embed, const float* __restrict__ W_ih2,
    const float* __restrict__ bs2,
    const float* __restrict__ W_out, const float* __restrict__ b_out,
    const float4* __restrict__ Wp1, float* __restrict__ X1t, float* __restrict__ E2,
    float* __restrict__ hE, float* __restrict__ cE,
    unsigned* __restrict__ cnt, float* __restrict__ out) {
    __shared__ __align__(16) float smem[16 * 68 + 16 * 132];
    const int blk = blockIdx.x;
    const int tid = threadIdx.x;

    if (blk < GX1) {
        // ---- X1 gemm: chunk t, rows = batches ----
        int t = blk >> 3, nx = blk & 7;
        gemm_body(input, (size_t)T_IN * 4096, (size_t)t * 4096, W_ih1, bs1,
                  X1t + (size_t)t * CH, 1, nx * 128, 4096, smem);
        __syncthreads();
        if (tid == 0)
            __hip_atomic_fetch_add(&cnt[t * 32], 1u,
                                   __ATOMIC_RELAXED, __HIP_MEMORY_SCOPE_AGENT);
    } else if (blk < GX1 + GE2) {
        // ---- E2 gemm: E2 = embed @ W_ih2^T + bs2 ----
        int e = blk - GX1, my = e >> 3, nx = e & 7;
        gemm_body(embed, 256, (size_t)my * 64 * 256, W_ih2, bs2,
                  E2 + (size_t)my * 64 * 1024, 0, nx * 128, 256, smem);
    } else if (blk < GX1 + GE2 + GD0) {
        // ---- dec0: l=0 logits broadcast + SOS symbols ----
        int bx = blk - (GX1 + GE2);
        float* es = smem;
        int v = bx * 256 + tid;
        es[tid] = embed[256 + tid];  // row SOS=1
        __syncthreads();
        float a = 0.f, a2 = 0.f;
        const float* wr = W_out + (size_t)v * 256;
        for (int k = 0; k < 256; k += 8) {
            float4 w0 = *(const float4*)(wr + k);
            float4 w1 = *(const float4*)(wr + k + 4);
            a  = fmaf(es[k+0],w0.x,fmaf(es[k+1],w0.y,fmaf(es[k+2],w0.z,fmaf(es[k+3],w0.w,a))));
            a2 = fmaf(es[k+4],w1.x,fmaf(es[k+5],w1.y,fmaf(es[k+6],w1.z,fmaf(es[k+7],w1.w,a2))));
        }
        float lg = a + a2 + b_out[v];
        for (int b = 0; b < B_SZ; ++b) out[(size_t)b * L_DEC * V_SZ + v] = lg;
        if (bx == 0 && tid < B_SZ) out[SYMBASE + tid * L_DEC] = 1.0f;
    } else {
        // ---- encoder: one block per batch; consumes X1 chunks as they land ----
        int b = blk - (GX1 + GE2 + GD0);
        float* hs = smem;          // 256
        float* cs = smem + 256;    // 256
        float* gb = smem + 512;    // 1024
        hs[tid] = 0.f; cs[tid] = 0.f;
        __syncthreads();
        const float4* hq = (const float4*)hs;
        for (int t = 0; t < T_IN; ++t) {
            if (tid == 0) {
                while (__hip_atomic_load(&cnt[t * 32], __ATOMIC_RELAXED,
                                         __HIP_MEMORY_SCOPE_AGENT) != 8u)
                    __builtin_amdgcn_s_sleep(8);
            }
            __syncthreads();
            asm volatile("" ::: "memory");
            float a0 = 0.f, a1 = 0.f, a2 = 0.f, a3 = 0.f;
#pragma unroll 8
            for (int kq = 0; kq < 64; ++kq) {
                float4 h4 = hq[kq];
                float4 w0 = Wp1[(kq << 10) + tid];
                float4 w1 = Wp1[(kq << 10) + tid + 256];
                float4 w2 = Wp1[(kq << 10) + tid + 512];
                float4 w3 = Wp1[(kq << 10) + tid + 768];
                a0 = fmaf(h4.x,w0.x,fmaf(h4.y,w0.y,fmaf(h4.z,w0.z,fmaf(h4.w,w0.w,a0))));
                a1 = fmaf(h4.x,w1.x,fmaf(h4.y,w1.y,fmaf(h4.z,w1.z,fmaf(h4.w,w1.w,a1))));
                a2 = fmaf(h4.x,w2.x,fmaf(h4.y,w2.y,fmaf(h4.z,w2.z,fmaf(h4.w,w2.w,a2))));
                a3 = fmaf(h4.x,w3.x,fmaf(h4.y,w3.y,fmaf(h4.z,w3.z,fmaf(h4.w,w3.w,a3))));
            }
            gb[tid] = a0; gb[256 + tid] = a1; gb[512 + tid] = a2; gb[768 + tid] = a3;
            __syncthreads();
            const float* xr = X1t + (size_t)t * CH + b * 1024;
            float gi = gb[tid]       + xr[tid];
            float gf = gb[256 + tid] + xr[256 + tid];
            float gg = gb[512 + tid] + xr[512 + tid];
            float go = gb[768 + tid] + xr[768 + tid];
            float cn = sigf(gf) * cs[tid] + sigf(gi) * tanhf(gg);
            float hn = sigf(go) * tanhf(cn);
            cs[tid] = cn; hs[tid] = hn;
            if (t == T_IN - 1) { hE[b * 256 + tid] = hn; cE[b * 256 + tid] = cn; }
        }
    }
}

// ---------------- decoder: 128 blocks x 256 thr, W-stationary, 2 exchanges/step ------
// Block x owns LSTM2 units {2x,2x+1} (Whh2 slice in LDS) + logit cols [48x,48x+48).
__global__ __launch_bounds__(256) void dec_exch(
    const float* __restrict__ Whh2, const float* __restrict__ E2,
    const float* __restrict__ Wout, const float* __restrict__ bout,
    const float* __restrict__ hE, const float* __restrict__ cE,
    float* __restrict__ hRot, u64* __restrict__ parts,
    int* __restrict__ flagA, int* __restrict__ flagB,
    float* __restrict__ out) {
    __shared__ __align__(16) float4 hs4[4096];   // swizzled h[64][256], 64KB
    __shared__ __align__(16) float ws2[8 * 256]; // Whh2 slice, 8KB
    __shared__ float gbuf[4][2][64];
    __shared__ u64 pm[4][64];
    __shared__ float cls[2][64];
    __shared__ int ssym[64];
    const int tid = threadIdx.x;
    const int x = blockIdx.x;
    const int b = tid & 63;
    const int u0 = x * 2;

    // Whh2 slice rows {gt*256 + u0 + du}
    for (int i = tid; i < 2048; i += 256) {
        int r = i >> 8, k = i & 255;
        int row = (r >> 1) * 256 + u0 + (r & 1);
        ws2[r * 256 + k] = Whh2[(size_t)row * 256 + k];
    }
    {   // stage h_enc, c, sym
        const float4* hf = (const float4*)hE;
        for (int i = tid; i < 4096; i += 256) {
            int bb = i >> 6, s = i & 63;
            hs4[(bb << 6) + (s ^ (bb & 7))] = hf[i];
        }
        if (tid < 128) cls[tid >> 6][tid & 63] = cE[(size_t)(tid & 63) * 256 + u0 + (tid >> 6)];
        if (tid < 64) ssym[tid] = 1;
    }
    __syncthreads();

    const float4* ws2q = (const float4*)ws2;
    for (int l = 0; l < L_DEC - 1; ++l) {
        float* hcur = hRot + (size_t)l * HSTRIDE;
        u64* pcur = parts + (size_t)l * PSTRIDE;
        // ---- LSTM2 gates: thread (b, gt) -> 2 dots (du=0,1) ----
        {
            int gt = tid >> 6;
            float a0 = 0.f, a1 = 0.f;
            const float4* wA = ws2q + (gt * 2) * 64;
            const float4* wB = ws2q + (gt * 2 + 1) * 64;
#pragma unroll 8
            for (int k4 = 0; k4 < 64; ++k4) {
                float4 hv = hs4[(b << 6) + (k4 ^ (b & 7))];
                float4 w0 = wA[k4], w1 = wB[k4];
                a0 = fmaf(hv.x,w0.x,fmaf(hv.y,w0.y,fmaf(hv.z,w0.z,fmaf(hv.w,w0.w,a0))));
                a1 = fmaf(hv.x,w1.x,fmaf(hv.y,w1.y,fmaf(hv.z,w1.z,fmaf(hv.w,w1.w,a1))));
            }
            float2 e2 = *(const float2*)(E2 + ((size_t)ssym[b] << 10) + gt * 256 + u0);
            gbuf[gt][0][b] = a0 + e2.x;
            gbuf[gt][1][b] = a1 + e2.y;
        }
        __syncthreads();
        if (tid < 128) {
            int du = tid >> 6, bb = tid & 63;
            float gi = gbuf[0][du][bb], gf = gbuf[1][du][bb];
            float gg = gbuf[2][du][bb], go_ = gbuf[3][du][bb];
            float cn = sigf(gf) * cls[du][bb] + sigf(gi) * tanhf(gg);
            cls[du][bb] = cn;
            float hn = sigf(go_) * tanhf(cn);
            __hip_atomic_store(&hcur[(size_t)bb * 256 + u0 + du], hn,
                               __ATOMIC_RELAXED, __HIP_MEMORY_SCOPE_AGENT);
        }
        __syncthreads();   // drains stores
        if (tid == 0)
            __hip_atomic_store(&flagA[(l * NDB + x) * 32], l + 1,
                               __ATOMIC_RELAXED, __HIP_MEMORY_SCOPE_AGENT);
        if (tid < 64) {
            const int* f0 = &flagA[(l * NDB + tid) * 32];
            const int* f1 = &flagA[(l * NDB + tid + 64) * 32];
            while (true) {
                int v0 = __hip_atomic_load(f0, __ATOMIC_RELAXED, __HIP_MEMORY_SCOPE_AGENT);
                int v1 = __hip_atomic_load(f1, __ATOMIC_RELAXED, __HIP_MEMORY_SCOPE_AGENT);
                if (__all(v0 == l + 1 && v1 == l + 1)) break;
                __builtin_amdgcn_s_sleep(1);
            }
        }
        __syncthreads();
        asm volatile("" ::: "memory");
        {   // stage h_{l+1} (plain coalesced; rotating + guarded addresses)
            const float4* hf2 = (const float4*)hcur;
            for (int i = tid; i < 4096; i += 256) {
                int bb = i >> 6, s = i & 63;
                hs4[(bb << 6) + (s ^ (bb & 7))] = hf2[i];
            }
        }
        __syncthreads();
        // ---- logits: wave w -> 12 cols, lane = batch ----
        {
            int w = tid >> 6;
            int v0 = __builtin_amdgcn_readfirstlane(x * 48 + w * 12);
            float acc[12];
#pragma unroll
            for (int c = 0; c < 12; ++c) acc[c] = 0.f;
            const float* wbase = Wout + (size_t)v0 * 256;
#pragma unroll 4
            for (int k4 = 0; k4 < 64; ++k4) {
                float4 hv = hs4[(b << 6) + (k4 ^ (b & 7))];
#pragma unroll
                for (int c = 0; c < 12; ++c) {
                    float4 ww = *(const float4*)(wbase + (size_t)c * 256 + (k4 << 2));
                    acc[c] = fmaf(hv.x, ww.x, fmaf(hv.y, ww.y,
                             fmaf(hv.z, ww.z, fmaf(hv.w, ww.w, acc[c]))));
                }
            }
            u64 best = 0ull;
            float* orow = out + (size_t)(b * L_DEC + l + 1) * V_SZ + v0;
#pragma unroll
            for (int c = 0; c < 12; ++c) {
                float lg = acc[c] + bout[v0 + c];
                orow[c] = lg;
                u64 p = packmax(lg, v0 + c);
                if (p > best) best = p;
            }
            pm[w][b] = best;
        }
        __syncthreads();
        if (tid < 64) {
            u64 m = pm[0][tid];
            if (pm[1][tid] > m) m = pm[1][tid];
            if (pm[2][tid] > m) m = pm[2][tid];
            if (pm[3][tid] > m) m = pm[3][tid];
            __hip_atomic_store(&pcur[(size_t)tid * NDB + x], m,
                               __ATOMIC_RELAXED, __HIP_MEMORY_SCOPE_AGENT);
        }
        __syncthreads();
        if (tid == 0)
            __hip_atomic_store(&flagB[(l * NDB + x) * 32], l + 1,
                               __ATOMIC_RELAXED, __HIP_MEMORY_SCOPE_AGENT);
        if (tid < 64) {
            const int* f0 = &flagB[(l * NDB + tid) * 32];
            const int* f1 = &flagB[(l * NDB + tid + 64) * 32];
            while (true) {
                int v0 = __hip_atomic_load(f0, __ATOMIC_RELAXED, __HIP_MEMORY_SCOPE_AGENT);
                int v1 = __hip_atomic_load(f1, __ATOMIC_RELAXED, __HIP_MEMORY_SCOPE_AGENT);
                if (__all(v0 == l + 1 && v1 == l + 1)) break;
                __builtin_amdgcn_s_sleep(1);
            }
        }
        __syncthreads();
        asm volatile("" ::: "memory");
        {   // global argmax: thread (b, w) scans 32 partials (plain loads)
            int w = tid >> 6;
            const u64* pr = pcur + (size_t)b * NDB + w * 32;
            u64 m = 0ull;
#pragma unroll 8
            for (int j = 0; j < 32; ++j) { u64 p = pr[j]; if (p > m) m = p; }
            pm[w][b] = m;
        }
        __syncthreads();
        if (tid < 64) {
            u64 m = pm[0][tid];
            if (pm[1][tid] > m) m = pm[1][tid];
            if (pm[2][tid] > m) m = pm[2][tid];
            if (pm[3][tid] > m) m = pm[3][tid];
            int idx = (int)(0x7FFFFFFFu - (unsigned)(m & 0xFFFFFFFFu));
            ssym[tid] = idx;
            if (x == tid) out[SYMBASE + tid * L_DEC + l + 1] = (float)idx;
        }
        __syncthreads();
    }
}

extern "C" void kernel_launch(void* const* d_in, const int* in_sizes, int n_in,
                              void* d_out, int out_size, void* d_ws, size_t ws_size,
                              hipStream_t stream) {
    const float* input = (const float*)d_in[0];
    // d_in[1] target_lengths: all == L_DEC, unused
    const float* embed = (const float*)d_in[2];
    const float* W_out = (const float*)d_in[3];
    const float* b_out = (const float*)d_in[4];
    const float* W_ih1 = (const float*)d_in[5];
    const float* W_hh1 = (const float*)d_in[6];
    const float* b_ih1 = (const float*)d_in[7];
    const float* b_hh1 = (const float*)d_in[8];
    const float* W_ih2 = (const float*)d_in[9];
    const float* W_hh2 = (const float*)d_in[10];
    const float* b_ih2 = (const float*)d_in[11];
    const float* b_hh2 = (const float*)d_in[12];
    float* out = (float*)d_out;

    float* ws = (float*)d_ws;
    float* X1t  = ws; ws += (size_t)T_IN * CH;        // t-chunked X1 (+guards)
    float* E2   = ws; ws += 6144 * 1024;              // embed @ Wih2^T + bs2
    float* Wp1  = ws; ws += 256 * 1024;               // Whh1 k-major packed
    float* hE   = ws; ws += 16384;
    float* cE   = ws; ws += 16384;
    float* bs1  = ws; ws += 1024;
    float* bs2  = ws; ws += 1024;
    float* hRot = ws; ws += (size_t)(L_DEC - 1) * HSTRIDE;
    u64* parts  = (u64*)ws; ws += (size_t)2 * (L_DEC - 1) * PSTRIDE;
    int* flagA  = (int*)ws; ws += 29 * NDB * 32;
    int* flagB  = (int*)ws; ws += 29 * NDB * 32;
    unsigned* cnt = (unsigned*)ws; ws += 80 * 32;
    if (ws_size < (size_t)((float*)ws - (float*)d_ws) * 4) return;

    biasum<<<4, 256, 0, stream>>>(b_ih1, b_hh1, b_ih2, b_hh2, bs1, bs2);
    init0<<<256, 256, 0, stream>>>(flagA, flagB, cnt);
    packWk<<<1024, 256, 0, stream>>>(W_hh1, Wp1);
    mega1<<<NB1, 256, 0, stream>>>(input, W_ih1, bs1, embed, W_ih2, bs2,
                                   W_out, b_out, (const float4*)Wp1,
                                   X1t, E2, hE, cE, cnt, out);
    dec_exch<<<NDB, 256, 0, stream>>>(W_hh2, E2, W_out, b_out, hE, cE,
                                      hRot, parts, flagA, flagB, out);
}

// Round 7
// 2673.691 us; speedup vs baseline: 1.4560x; 1.0409x over previous
//
#include <hip/hip_runtime.h>
#include <math.h>

#define B_SZ 64
#define T_IN 80
#define H_SZ 256
#define V_SZ 6144
#define L_DEC 30
#define SYMBASE (B_SZ * L_DEC * V_SZ)
#define CH 66560            // X1 t-chunk stride floats (64*1024 + guard)
#define HSTR 16640          // h rotating stride floats (16384 + guard)
#define PSTR 2048           // argmax partials per step (u64)
#define FSTR 16             // flag stride (ints, 64B)
#define NENC 256            // encoder blocks (32 per XCD-group)
#define NGEM 640            // X1 gemm blocks (80 t x 8 n)

typedef unsigned long long u64;

#define AT_STORE(p, v) __hip_atomic_store((p), (v), __ATOMIC_RELAXED, __HIP_MEMORY_SCOPE_AGENT)
#define AT_LOAD(p)     __hip_atomic_load((p), __ATOMIC_RELAXED, __HIP_MEMORY_SCOPE_AGENT)

__device__ __forceinline__ float sigf(float x) { return 1.f / (1.f + expf(-x)); }

// monotone float->uint pack, first-index tie-break in low bits (never 0)
__device__ __forceinline__ u64 packmax(float v, int idx) {
    unsigned u = __float_as_uint(v);
    u = (u & 0x80000000u) ? ~u : (u | 0x80000000u);
    return ((u64)u << 32) | (unsigned)(0x7FFFFFFF - idx);
}

// gate-column permutation: n(0..1023) -> j*32 + uu*4 + gt  (u = n&255 = j*8+uu, gt = n>>8)
__device__ __forceinline__ int permcol(int n) {
    int u = n & 255, gt = n >> 8;
    return ((u >> 3) << 5) + ((u & 7) << 2) + gt;
}

// ---------------- bias sums ----------------
__global__ void biasum(const float* a1, const float* b1, const float* a2, const float* b2,
                       float* o1, float* o2) {
    int i = blockIdx.x * 256 + threadIdx.x;
    if (i < 1024) { o1[i] = a1[i] + b1[i]; o2[i] = a2[i] + b2[i]; }
}

// ---------------- init: zero flags + chunk counters ----------------
__global__ void init0(int* encFlag, int* dFlagA, int* dFlagB, unsigned* cnt) {
    int i = blockIdx.x * 256 + threadIdx.x;            // 256 blocks -> 65536 threads
    for (int k = i; k < 80 * 256 * FSTR; k += 65536) encFlag[k] = 0;
    for (int k = i; k < 29 * 256 * FSTR; k += 65536) { dFlagA[k] = 0; dFlagB[k] = 0; }
    if (i < 80 * 32) cnt[i] = 0u;
}

// ---------------- gemm body: C[64][1024] = A[64 rows][K] @ W[1024][K]^T + bias ----
// BM=64, BN=128, BK=16, 256 threads, 4x8 micro-tile; gate-permuted C columns
__device__ __forceinline__ void gemm_body(
    const float* __restrict__ A, size_t astride, size_t aoff,
    const float* __restrict__ W, const float* __restrict__ bias,
    float* __restrict__ Cbase, int atomicC, int n0, int K, float* smem) {
    float* As = smem;              // [16][68]
    float* Bs = smem + 16 * 68;    // [16][132]
    const int tid = threadIdx.x;
    const int tx = tid & 15, ty = tid >> 4;
    const int a_m = tid >> 2, a_k = (tid & 3) * 4;
    const int b_n = tid >> 1, b_k = (tid & 1) * 8;

    float acc[4][8];
#pragma unroll
    for (int r = 0; r < 4; ++r)
#pragma unroll
        for (int c = 0; c < 8; ++c) acc[r][c] = 0.f;

    for (int k0 = 0; k0 < K; k0 += 16) {
        float4 av  = *(const float4*)(A + (size_t)a_m * astride + aoff + k0 + a_k);
        float4 bv0 = *(const float4*)(W + (size_t)(n0 + b_n) * K + k0 + b_k);
        float4 bv1 = *(const float4*)(W + (size_t)(n0 + b_n) * K + k0 + b_k + 4);
        __syncthreads();
        As[(a_k + 0) * 68 + a_m] = av.x; As[(a_k + 1) * 68 + a_m] = av.y;
        As[(a_k + 2) * 68 + a_m] = av.z; As[(a_k + 3) * 68 + a_m] = av.w;
        Bs[(b_k + 0) * 132 + b_n] = bv0.x; Bs[(b_k + 1) * 132 + b_n] = bv0.y;
        Bs[(b_k + 2) * 132 + b_n] = bv0.z; Bs[(b_k + 3) * 132 + b_n] = bv0.w;
        Bs[(b_k + 4) * 132 + b_n] = bv1.x; Bs[(b_k + 5) * 132 + b_n] = bv1.y;
        Bs[(b_k + 6) * 132 + b_n] = bv1.z; Bs[(b_k + 7) * 132 + b_n] = bv1.w;
        __syncthreads();
#pragma unroll
        for (int kk = 0; kk < 16; ++kk) {
            float4 a0 = *(const float4*)&As[kk * 68 + ty * 4];
            float4 b0 = *(const float4*)&Bs[kk * 132 + tx * 8];
            float4 b1 = *(const float4*)&Bs[kk * 132 + tx * 8 + 4];
            float ar[4] = {a0.x, a0.y, a0.z, a0.w};
            float br[8] = {b0.x, b0.y, b0.z, b0.w, b1.x, b1.y, b1.z, b1.w};
#pragma unroll
            for (int r = 0; r < 4; ++r)
#pragma unroll
                for (int c = 0; c < 8; ++c)
                    acc[r][c] = fmaf(ar[r], br[c], acc[r][c]);
        }
    }
#pragma unroll
    for (int r = 0; r < 4; ++r) {
        int row = ty * 4 + r;
#pragma unroll
        for (int c = 0; c < 8; ++c) {
            int n = n0 + tx * 8 + c;
            float v = acc[r][c] + bias[n];
            float* dst = Cbase + (size_t)row * 1024 + permcol(n);
            if (atomicC) AT_STORE(dst, v);
            else *dst = v;
        }
    }
}

// ---------------- E2p gemm: embed @ W_ih2^T + bs2, permuted cols ----------------
__global__ __launch_bounds__(256) void e2gemm(const float* __restrict__ embed,
                                              const float* __restrict__ W_ih2,
                                              const float* __restrict__ bs2,
                                              float* __restrict__ E2p) {
    __shared__ __align__(16) float smem[16 * 68 + 16 * 132];
    int my = blockIdx.y, nx = blockIdx.x;
    gemm_body(embed + (size_t)my * 64 * 256, 256, 0, W_ih2, bs2,
              E2p + (size_t)my * 64 * 1024, 0, nx * 128, 256, smem);
}

// ---------------- step-0 outputs: dec_o0 broadcast + SOS symbols ----------------
__global__ __launch_bounds__(256) void dec0(const float* __restrict__ embed,
                                            const float* __restrict__ Wout,
                                            const float* __restrict__ bout,
                                            float* __restrict__ out) {
    __shared__ float es[256];
    int tid = threadIdx.x;
    int v = blockIdx.x * 256 + tid;
    es[tid] = embed[256 + tid];  // row SOS=1
    __syncthreads();
    float a = 0.f, a2 = 0.f;
    const float* wr = Wout + (size_t)v * 256;
    for (int k = 0; k < 256; k += 8) {
        float4 w0 = *(const float4*)(wr + k);
        float4 w1 = *(const float4*)(wr + k + 4);
        a  = fmaf(es[k+0],w0.x,fmaf(es[k+1],w0.y,fmaf(es[k+2],w0.z,fmaf(es[k+3],w0.w,a))));
        a2 = fmaf(es[k+4],w1.x,fmaf(es[k+5],w1.y,fmaf(es[k+6],w1.z,fmaf(es[k+7],w1.w,a2))));
    }
    float lg = a + a2 + bout[v];
    for (int b = 0; b < B_SZ; ++b) out[(size_t)b * L_DEC * V_SZ + v] = lg;
    if (blockIdx.x == 0 && tid < B_SZ) out[SYMBASE + tid * L_DEC] = 1.0f;
}

// ---------------- mega: encoder (256 XCD-grouped blocks) ∥ X1 gemm (640 blocks) ----
// Encoder block (g = blk&7, j = blk>>3): batches 8g..8g+7, units 8j..8j+7.
// Whh1 slice (32 rows x 256) lives in LDS for all 80 steps; intra-group h exchange.
__global__ __launch_bounds__(256) void mega(
    const float* __restrict__ input, const float* __restrict__ W_ih1,
    const float* __restrict__ bs1, const float* __restrict__ Whh1,
    float* __restrict__ X1p, float* __restrict__ hRotE, float* __restrict__ cEnc,
    unsigned* __restrict__ cnt, int* __restrict__ encFlag) {
    __shared__ __align__(16) float smem[8192 + 2048 + 264 + 64];
    const int tid = threadIdx.x;
    const int blk = blockIdx.x;

    if (blk >= NENC) {   // ---- X1 gemm: chunk t of 64 batch-rows ----
        int bg = blk - NENC, t = bg >> 3, nx = bg & 7;
        gemm_body(input, (size_t)T_IN * 4096, (size_t)t * 4096, W_ih1, bs1,
                  X1p + (size_t)t * CH, 1, nx * 128, 4096, smem);
        __syncthreads();
        if (tid == 0)
            __hip_atomic_fetch_add(&cnt[t * 32], 1u,
                                   __ATOMIC_RELAXED, __HIP_MEMORY_SCOPE_AGENT);
        return;
    }

    // ---- encoder ----
    const int g = blk & 7, j = blk >> 3;
    float* wsl  = smem;            // [32][256] swizzled
    float* hgrp = smem + 8192;     // [8][256]
    float* gbuf = smem + 10240;    // [8][33]
    float* cls  = smem + 10504;    // [64]
    float4* wsl4  = (float4*)wsl;
    float4* hgrp4 = (float4*)hgrp;

    for (int rr = 0; rr < 32; ++rr) {   // W slice: row rr = (uu=rr>>2, gt=rr&3)
        int row = (rr & 3) * 256 + j * 8 + (rr >> 2);
        float w = Whh1[(size_t)row * 256 + tid];
        wsl[rr * 256 + (((tid >> 2) ^ (rr & 15)) << 2) + (tid & 3)] = w;
    }
    for (int i = tid; i < 2048; i += 256) hgrp[i] = 0.f;
    if (tid < 64) cls[tid] = 0.f;
    __syncthreads();

    const int b = tid >> 5, r = tid & 31, rx = r & 15;
    for (int t = 0; t < T_IN; ++t) {
        if (tid == 0) {
            while (AT_LOAD(&cnt[t * 32]) < 8u) __builtin_amdgcn_s_sleep(4);
        }
        __syncthreads();
        asm volatile("" ::: "memory");
        float acc = X1p[(size_t)t * CH + ((size_t)(g * 8 + b) << 10) + j * 32 + r];
        const float4* hb4 = hgrp4 + (b << 6);
#pragma unroll 8
        for (int kq = 0; kq < 64; ++kq) {
            float4 w4 = wsl4[(r << 6) + (kq ^ rx)];
            float4 h4 = hb4[kq];
            acc = fmaf(h4.x, w4.x, fmaf(h4.y, w4.y,
                  fmaf(h4.z, w4.z, fmaf(h4.w, w4.w, acc))));
        }
        gbuf[b * 33 + r] = acc;
        __syncthreads();
        float* hstep = hRotE + (size_t)t * HSTR;
        if (tid < 64) {
            int bb = tid >> 3, uu = tid & 7;
            float gi = gbuf[bb * 33 + uu * 4 + 0];
            float gf = gbuf[bb * 33 + uu * 4 + 1];
            float gg = gbuf[bb * 33 + uu * 4 + 2];
            float go = gbuf[bb * 33 + uu * 4 + 3];
            float cn = sigf(gf) * cls[tid] + sigf(gi) * tanhf(gg);
            cls[tid] = cn;
            float hn = sigf(go) * tanhf(cn);
            AT_STORE(&hstep[((size_t)(g * 8 + bb) << 8) + j * 8 + uu], hn);
            if (t == T_IN - 1) cEnc[((g * 8 + bb) << 8) + j * 8 + uu] = cn;
        }
        __syncthreads();   // drains h' stores before flag
        if (tid == 0) AT_STORE(&encFlag[(t * 256 + blk) * FSTR], t + 1);
        if (tid < 32) {
            const int* fp = &encFlag[(t * 256 + g + tid * 8) * FSTR];
            while (AT_LOAD(fp) != t + 1) __builtin_amdgcn_s_sleep(1);
        }
        __syncthreads();
        asm volatile("" ::: "memory");
        const float4* hsrc = (const float4*)hstep + (size_t)(g * 8) * 64;
        for (int i = tid; i < 512; i += 256) hgrp4[i] = hsrc[i];
        __syncthreads();
    }
}

// ---------------- decoder: 256 blocks, XCD-group (g,j); zero cross-group sync ----
__global__ __launch_bounds__(256) void dec_xcd(
    const float* __restrict__ Whh2, const float* __restrict__ E2p,
    const float* __restrict__ Wout, const float* __restrict__ bout,
    const float* __restrict__ hEnc, const float* __restrict__ cEnc,
    float* __restrict__ hRotD, u64* __restrict__ partsD,
    int* __restrict__ dFlagA, int* __restrict__ dFlagB,
    float* __restrict__ out) {
    __shared__ __align__(16) float smem[8192 + 2048 + 2048 + 264 + 64];
    __shared__ u64 pmW[4 * 64];
    __shared__ int ssym[8];
    float* wsl  = smem;             // [32][256] swizzled
    float* hgrp = smem + 8192;      // [8][256]  (gates layout)
    float* hIf  = smem + 10240;     // [8][256]  (logits i-major layout)
    float* gbuf = smem + 12288;     // [8][33]
    float* cls  = smem + 12552;     // [64]
    float4* wsl4  = (float4*)wsl;
    float4* hgrp4 = (float4*)hgrp;
    float4* hI4   = (float4*)hIf;
    const int tid = threadIdx.x;
    const int blk = blockIdx.x;
    const int g = blk & 7, j = blk >> 3;

    for (int rr = 0; rr < 32; ++rr) {
        int row = (rr & 3) * 256 + j * 8 + (rr >> 2);
        float w = Whh2[(size_t)row * 256 + tid];
        wsl[rr * 256 + (((tid >> 2) ^ (rr & 15)) << 2) + (tid & 3)] = w;
    }
    if (tid < 64) cls[tid] = cEnc[((size_t)(g * 8 + (tid >> 3)) << 8) + j * 8 + (tid & 7)];
    if (tid < 8) ssym[tid] = 1;   // SOS
    {   // initial stage from encoder h (kernel-boundary coherence)
        const float4* hsrc = (const float4*)hEnc + (size_t)(g * 8) * 64;
        for (int i = tid; i < 512; i += 256) {
            float4 v = hsrc[i];
            int bb = i >> 6, q = i & 63;
            hgrp4[i] = v;
            hI4[((q & 7) << 6) + bb * 8 + (q >> 3)] = v;
        }
    }
    __syncthreads();

    const int b = tid >> 5, r = tid & 31, rx = r & 15;
    const int w = tid >> 6, lane = tid & 63;
    const int lb = lane >> 3, ls = lane & 7;
    const float4* WoQ = (const float4*)Wout;

    for (int l = 0; l < L_DEC - 1; ++l) {
        // ---- LSTM2 gates ----
        {
            float acc = E2p[((size_t)ssym[b] << 10) + j * 32 + r];
            const float4* hb4 = hgrp4 + (b << 6);
#pragma unroll 8
            for (int kq = 0; kq < 64; ++kq) {
                float4 w4 = wsl4[(r << 6) + (kq ^ rx)];
                float4 h4 = hb4[kq];
                acc = fmaf(h4.x, w4.x, fmaf(h4.y, w4.y,
                      fmaf(h4.z, w4.z, fmaf(h4.w, w4.w, acc))));
            }
            gbuf[b * 33 + r] = acc;
        }
        __syncthreads();
        float* hstep = hRotD + (size_t)l * HSTR;
        if (tid < 64) {
            int bb = tid >> 3, uu = tid & 7;
            float gi = gbuf[bb * 33 + uu * 4 + 0];
            float gf = gbuf[bb * 33 + uu * 4 + 1];
            float gg = gbuf[bb * 33 + uu * 4 + 2];
            float go = gbuf[bb * 33 + uu * 4 + 3];
            float cn = sigf(gf) * cls[tid] + sigf(gi) * tanhf(gg);
            cls[tid] = cn;
            float hn = sigf(go) * tanhf(cn);
            AT_STORE(&hstep[((size_t)(g * 8 + bb) << 8) + j * 8 + uu], hn);
        }
        __syncthreads();
        if (tid == 0) AT_STORE(&dFlagA[(l * 256 + blk) * FSTR], l + 1);
        if (tid < 32) {
            const int* fp = &dFlagA[(l * 256 + g + tid * 8) * FSTR];
            while (AT_LOAD(fp) != l + 1) __builtin_amdgcn_s_sleep(1);
        }
        __syncthreads();
        asm volatile("" ::: "memory");
        {   // stage h_{l+1}: both layouts
            const float4* hsrc = (const float4*)hstep + (size_t)(g * 8) * 64;
            for (int i = tid; i < 512; i += 256) {
                float4 v = hsrc[i];
                int bb = i >> 6, q = i & 63;
                hgrp4[i] = v;
                hI4[((q & 7) << 6) + bb * 8 + (q >> 3)] = v;
            }
        }
        __syncthreads();

        // ---- logits: wave w -> 48 cols; lane = (batch lb, k-seg ls) ----
        {
            int c0 = j * 192 + w * 48;
            u64 best = 0ull;
            float* obase = out + ((size_t)((g * 8 + lb) * L_DEC + l + 1)) * V_SZ;
            for (int cc = 0; cc < 48; ++cc) {
                int c = c0 + cc;
                const float4* wr4 = WoQ + ((size_t)c << 6) + (ls << 3);
                float a = 0.f;
#pragma unroll
                for (int i = 0; i < 8; ++i) {
                    float4 w4 = wr4[i];
                    float4 h4 = hI4[(i << 6) + (lb << 3) + ls];
                    a = fmaf(h4.x, w4.x, fmaf(h4.y, w4.y,
                        fmaf(h4.z, w4.z, fmaf(h4.w, w4.w, a))));
                }
                a += __shfl_xor(a, 1);
                a += __shfl_xor(a, 2);
                a += __shfl_xor(a, 4);
                float lg = a + bout[c];
                if (ls == 0) obase[c] = lg;
                u64 p = packmax(lg, c);
                if (p > best) best = p;
            }
            pmW[(w << 6) + lane] = best;
        }
        __syncthreads();
        u64* pstep = partsD + (size_t)l * PSTR;
        if (tid < 8) {   // per-batch block-best over 4 waves (s=0 lanes)
            u64 m = pmW[tid * 8];
            if (pmW[64 + tid * 8] > m) m = pmW[64 + tid * 8];
            if (pmW[128 + tid * 8] > m) m = pmW[128 + tid * 8];
            if (pmW[192 + tid * 8] > m) m = pmW[192 + tid * 8];
            AT_STORE(&pstep[((size_t)(g * 8 + tid) << 5) + j], m);
        }
        __syncthreads();
        if (tid == 0) AT_STORE(&dFlagB[(l * 256 + blk) * FSTR], l + 1);
        if (tid < 32) {
            const int* fp = &dFlagB[(l * 256 + g + tid * 8) * FSTR];
            while (AT_LOAD(fp) != l + 1) __builtin_amdgcn_s_sleep(1);
        }
        __syncthreads();
        asm volatile("" ::: "memory");
        {   // group argmax: thread (bb = tid>>5, j2 = tid&31)
            int bb = tid >> 5, j2 = tid & 31;
            u64 m = pstep[((size_t)(g * 8 + bb) << 5) + j2];
#pragma unroll
            for (int off = 1; off < 32; off <<= 1) {
                u64 o = (u64)__shfl_xor((long long)m, off);
                if (o > m) m = o;
            }
            if (j2 == 0) ssym[bb] = (int)(0x7FFFFFFFu - (unsigned)(m & 0xFFFFFFFFu));
        }
        __syncthreads();
        if (j < 8 && tid == 0)
            out[SYMBASE + (g * 8 + j) * L_DEC + l + 1] = (float)ssym[j];
        __syncthreads();
    }
}

extern "C" void kernel_launch(void* const* d_in, const int* in_sizes, int n_in,
                              void* d_out, int out_size, void* d_ws, size_t ws_size,
                              hipStream_t stream) {
    const float* input = (const float*)d_in[0];
    // d_in[1] target_lengths: all == L_DEC, unused
    const float* embed = (const float*)d_in[2];
    const float* W_out = (const float*)d_in[3];
    const float* b_out = (const float*)d_in[4];
    const float* W_ih1 = (const float*)d_in[5];
    const float* W_hh1 = (const float*)d_in[6];
    const float* b_ih1 = (const float*)d_in[7];
    const float* b_hh1 = (const float*)d_in[8];
    const float* W_ih2 = (const float*)d_in[9];
    const float* W_hh2 = (const float*)d_in[10];
    const float* b_ih2 = (const float*)d_in[11];
    const float* b_hh2 = (const float*)d_in[12];
    float* out = (float*)d_out;

    float* ws = (float*)d_ws;
    float* X1p  = ws; ws += (size_t)T_IN * CH;            // 5.3M
    float* E2p  = ws; ws += (size_t)V_SZ * 1024;          // 6.3M
    float* hRotE = ws; ws += (size_t)T_IN * HSTR;         // 1.33M
    float* hRotD = ws; ws += (size_t)(L_DEC - 1) * HSTR;  // 0.48M
    float* cEnc = ws; ws += 16384;
    float* bs1  = ws; ws += 1024;
    float* bs2  = ws; ws += 1024;
    u64* partsD = (u64*)ws; ws += (size_t)2 * (L_DEC - 1) * PSTR;
    int* encFlag = (int*)ws; ws += 80 * 256 * FSTR;
    int* dFlagA  = (int*)ws; ws += 29 * 256 * FSTR;
    int* dFlagB  = (int*)ws; ws += 29 * 256 * FSTR;
    unsigned* cnt = (unsigned*)ws; ws += 80 * 32;
    if (ws_size < (size_t)((float*)ws - (float*)d_ws) * 4) return;

    biasum<<<4, 256, 0, stream>>>(b_ih1, b_hh1, b_ih2, b_hh2, bs1, bs2);
    init0<<<256, 256, 0, stream>>>(encFlag, dFlagA, dFlagB, cnt);
    e2gemm<<<dim3(8, 96), 256, 0, stream>>>(embed, W_ih2, bs2, E2p);
    dec0<<<24, 256, 0, stream>>>(embed, W_out, b_out, out);
    mega<<<NENC + NGEM, 256, 0, stream>>>(input, W_ih1, bs1, W_hh1,
                                          X1p, hRotE, cEnc, cnt, encFlag);
    dec_xcd<<<256, 256, 0, stream>>>(W_hh2, E2p, W_out, b_out,
                                     hRotE + (size_t)(T_IN - 1) * HSTR, cEnc,
                                     hRotD, partsD, dFlagA, dFlagB, out);
}

// Round 8
// 2016.861 us; speedup vs baseline: 1.9302x; 1.3257x over previous
//
#include <hip/hip_runtime.h>
#include <math.h>

#define B_SZ 64
#define T_IN 80
#define H_SZ 256
#define V_SZ 6144
#define L_DEC 30
#define SYMBASE (B_SZ * L_DEC * V_SZ)
#define CH 66560            // X1 t-chunk stride floats (64*1024 + guard)
#define HSTR 16640          // encoder h rotating stride floats
#define FSTR 16             // encoder flag stride (ints)
#define DFS 16              // decoder flag stride (ints)
#define NENC 256            // encoder blocks
#define NGEM 640            // X1 gemm blocks

typedef unsigned long long u64;

#define AT_STORE(p, v) __hip_atomic_store((p), (v), __ATOMIC_RELAXED, __HIP_MEMORY_SCOPE_AGENT)
#define AT_LOAD(p)     __hip_atomic_load((p), __ATOMIC_RELAXED, __HIP_MEMORY_SCOPE_AGENT)

__device__ __forceinline__ float sigf(float x) { return 1.f / (1.f + expf(-x)); }

// monotone float->uint pack, first-index tie-break in low bits (never 0)
__device__ __forceinline__ u64 packmax(float v, int idx) {
    unsigned u = __float_as_uint(v);
    u = (u & 0x80000000u) ? ~u : (u | 0x80000000u);
    return ((u64)u << 32) | (unsigned)(0x7FFFFFFF - idx);
}

// gate-column permutation: n -> j*32 + uu*4 + gt  (u = n&255 = j*8+uu, gt = n>>8)
__device__ __forceinline__ int permcol(int n) {
    int u = n & 255, gt = n >> 8;
    return ((u >> 3) << 5) + ((u & 7) << 2) + gt;
}

// ---------------- bias sums ----------------
__global__ void biasum(const float* a1, const float* b1, const float* a2, const float* b2,
                       float* o1, float* o2) {
    int i = blockIdx.x * 256 + threadIdx.x;
    if (i < 1024) { o1[i] = a1[i] + b1[i]; o2[i] = a2[i] + b2[i]; }
}

// ---------------- init: zero flags + chunk counters ----------------
__global__ void init0(int* encFlag, int* fA, int* fB, int* fG, unsigned* cnt) {
    int i = blockIdx.x * 256 + threadIdx.x;            // 65536 threads
    for (int k = i; k < 80 * 256 * FSTR; k += 65536) encFlag[k] = 0;
    if (i < 256 * DFS) { fA[i] = 0; fB[i] = 0; }
    if (i < 8 * DFS) fG[i] = 0;
    if (i < 80 * 32) cnt[i] = 0u;
}

// ---------------- gemm body: C[64][1024] = A@W^T + bias, gate-permuted cols ----
__device__ __forceinline__ void gemm_body(
    const float* __restrict__ A, size_t astride, size_t aoff,
    const float* __restrict__ W, const float* __restrict__ bias,
    float* __restrict__ Cbase, int atomicC, int n0, int K, float* smem) {
    float* As = smem;              // [16][68]
    float* Bs = smem + 16 * 68;    // [16][132]
    const int tid = threadIdx.x;
    const int tx = tid & 15, ty = tid >> 4;
    const int a_m = tid >> 2, a_k = (tid & 3) * 4;
    const int b_n = tid >> 1, b_k = (tid & 1) * 8;

    float acc[4][8];
#pragma unroll
    for (int r = 0; r < 4; ++r)
#pragma unroll
        for (int c = 0; c < 8; ++c) acc[r][c] = 0.f;

    for (int k0 = 0; k0 < K; k0 += 16) {
        float4 av  = *(const float4*)(A + (size_t)a_m * astride + aoff + k0 + a_k);
        float4 bv0 = *(const float4*)(W + (size_t)(n0 + b_n) * K + k0 + b_k);
        float4 bv1 = *(const float4*)(W + (size_t)(n0 + b_n) * K + k0 + b_k + 4);
        __syncthreads();
        As[(a_k + 0) * 68 + a_m] = av.x; As[(a_k + 1) * 68 + a_m] = av.y;
        As[(a_k + 2) * 68 + a_m] = av.z; As[(a_k + 3) * 68 + a_m] = av.w;
        Bs[(b_k + 0) * 132 + b_n] = bv0.x; Bs[(b_k + 1) * 132 + b_n] = bv0.y;
        Bs[(b_k + 2) * 132 + b_n] = bv0.z; Bs[(b_k + 3) * 132 + b_n] = bv0.w;
        Bs[(b_k + 4) * 132 + b_n] = bv1.x; Bs[(b_k + 5) * 132 + b_n] = bv1.y;
        Bs[(b_k + 6) * 132 + b_n] = bv1.z; Bs[(b_k + 7) * 132 + b_n] = bv1.w;
        __syncthreads();
#pragma unroll
        for (int kk = 0; kk < 16; ++kk) {
            float4 a0 = *(const float4*)&As[kk * 68 + ty * 4];
            float4 b0 = *(const float4*)&Bs[kk * 132 + tx * 8];
            float4 b1 = *(const float4*)&Bs[kk * 132 + tx * 8 + 4];
            float ar[4] = {a0.x, a0.y, a0.z, a0.w};
            float br[8] = {b0.x, b0.y, b0.z, b0.w, b1.x, b1.y, b1.z, b1.w};
#pragma unroll
            for (int r = 0; r < 4; ++r)
#pragma unroll
                for (int c = 0; c < 8; ++c)
                    acc[r][c] = fmaf(ar[r], br[c], acc[r][c]);
        }
    }
#pragma unroll
    for (int r = 0; r < 4; ++r) {
        int row = ty * 4 + r;
#pragma unroll
        for (int c = 0; c < 8; ++c) {
            int n = n0 + tx * 8 + c;
            float v = acc[r][c] + bias[n];
            float* dst = Cbase + (size_t)row * 1024 + permcol(n);
            if (atomicC) AT_STORE(dst, v);
            else *dst = v;
        }
    }
}

// ---------------- E2p gemm ----------------
__global__ __launch_bounds__(256) void e2gemm(const float* __restrict__ embed,
                                              const float* __restrict__ W_ih2,
                                              const float* __restrict__ bs2,
                                              float* __restrict__ E2p) {
    __shared__ __align__(16) float smem[16 * 68 + 16 * 132];
    int my = blockIdx.y, nx = blockIdx.x;
    gemm_body(embed + (size_t)my * 64 * 256, 256, 0, W_ih2, bs2,
              E2p + (size_t)my * 64 * 1024, 0, nx * 128, 256, smem);
}

// ---------------- step-0 outputs ----------------
__global__ __launch_bounds__(256) void dec0(const float* __restrict__ embed,
                                            const float* __restrict__ Wout,
                                            const float* __restrict__ bout,
                                            float* __restrict__ out) {
    __shared__ float es[256];
    int tid = threadIdx.x;
    int v = blockIdx.x * 256 + tid;
    es[tid] = embed[256 + tid];  // row SOS=1
    __syncthreads();
    float a = 0.f, a2 = 0.f;
    const float* wr = Wout + (size_t)v * 256;
    for (int k = 0; k < 256; k += 8) {
        float4 w0 = *(const float4*)(wr + k);
        float4 w1 = *(const float4*)(wr + k + 4);
        a  = fmaf(es[k+0],w0.x,fmaf(es[k+1],w0.y,fmaf(es[k+2],w0.z,fmaf(es[k+3],w0.w,a))));
        a2 = fmaf(es[k+4],w1.x,fmaf(es[k+5],w1.y,fmaf(es[k+6],w1.z,fmaf(es[k+7],w1.w,a2))));
    }
    float lg = a + a2 + bout[v];
    for (int b = 0; b < B_SZ; ++b) out[(size_t)b * L_DEC * V_SZ + v] = lg;
    if (blockIdx.x == 0 && tid < B_SZ) out[SYMBASE + tid * L_DEC] = 1.0f;
}

// ---------------- mega: encoder (256 XCD-grouped blocks) ∥ X1 gemm (640 blocks) ----
__global__ __launch_bounds__(256) void mega(
    const float* __restrict__ input, const float* __restrict__ W_ih1,
    const float* __restrict__ bs1, const float* __restrict__ Whh1,
    float* __restrict__ X1p, float* __restrict__ hRotE, float* __restrict__ cEnc,
    unsigned* __restrict__ cnt, int* __restrict__ encFlag) {
    __shared__ __align__(16) float smem[8192 + 2048 + 264 + 64];
    const int tid = threadIdx.x;
    const int blk = blockIdx.x;

    if (blk >= NENC) {   // ---- X1 gemm ----
        int bg = blk - NENC, t = bg >> 3, nx = bg & 7;
        gemm_body(input, (size_t)T_IN * 4096, (size_t)t * 4096, W_ih1, bs1,
                  X1p + (size_t)t * CH, 1, nx * 128, 4096, smem);
        __syncthreads();
        if (tid == 0)
            __hip_atomic_fetch_add(&cnt[t * 32], 1u,
                                   __ATOMIC_RELAXED, __HIP_MEMORY_SCOPE_AGENT);
        return;
    }

    // ---- encoder ----
    const int g = blk & 7, j = blk >> 3;
    float* wsl  = smem;            // [32][256] swizzled
    float* hgrp = smem + 8192;     // [8][256]
    float* gbuf = smem + 10240;    // [8][33]
    float* cls  = smem + 10504;    // [64]
    float4* wsl4  = (float4*)wsl;
    float4* hgrp4 = (float4*)hgrp;

    for (int rr = 0; rr < 32; ++rr) {
        int row = (rr & 3) * 256 + j * 8 + (rr >> 2);
        float w = Whh1[(size_t)row * 256 + tid];
        wsl[rr * 256 + (((tid >> 2) ^ (rr & 15)) << 2) + (tid & 3)] = w;
    }
    for (int i = tid; i < 2048; i += 256) hgrp[i] = 0.f;
    if (tid < 64) cls[tid] = 0.f;
    __syncthreads();

    const int b = tid >> 5, r = tid & 31, rx = r & 15;
    for (int t = 0; t < T_IN; ++t) {
        if (tid == 0) {
            while (AT_LOAD(&cnt[t * 32]) < 8u) __builtin_amdgcn_s_sleep(4);
        }
        __syncthreads();
        asm volatile("" ::: "memory");
        float acc = X1p[(size_t)t * CH + ((size_t)(g * 8 + b) << 10) + j * 32 + r];
        const float4* hb4 = hgrp4 + (b << 6);
#pragma unroll 8
        for (int kq = 0; kq < 64; ++kq) {
            float4 w4 = wsl4[(r << 6) + (kq ^ rx)];
            float4 h4 = hb4[kq];
            acc = fmaf(h4.x, w4.x, fmaf(h4.y, w4.y,
                  fmaf(h4.z, w4.z, fmaf(h4.w, w4.w, acc))));
        }
        gbuf[b * 33 + r] = acc;
        __syncthreads();
        float* hstep = hRotE + (size_t)t * HSTR;
        if (tid < 64) {
            int bb = tid >> 3, uu = tid & 7;
            float gi = gbuf[bb * 33 + uu * 4 + 0];
            float gf = gbuf[bb * 33 + uu * 4 + 1];
            float gg = gbuf[bb * 33 + uu * 4 + 2];
            float go = gbuf[bb * 33 + uu * 4 + 3];
            float cn = sigf(gf) * cls[tid] + sigf(gi) * tanhf(gg);
            cls[tid] = cn;
            float hn = sigf(go) * tanhf(cn);
            AT_STORE(&hstep[((size_t)(g * 8 + bb) << 8) + j * 8 + uu], hn);
            if (t == T_IN - 1) cEnc[((g * 8 + bb) << 8) + j * 8 + uu] = cn;
        }
        __syncthreads();
        if (tid == 0) AT_STORE(&encFlag[(t * 256 + blk) * FSTR], t + 1);
        if (tid < 32) {
            const int* fp = &encFlag[(t * 256 + g + tid * 8) * FSTR];
            while (AT_LOAD(fp) != t + 1) __builtin_amdgcn_s_sleep(1);
        }
        __syncthreads();
        asm volatile("" ::: "memory");
        const float4* hsrc = (const float4*)hstep + (size_t)(g * 8) * 64;
        for (int i = tid; i < 512; i += 256) hgrp4[i] = hsrc[i];
        __syncthreads();
    }
}

// ---------------- decoder: W_out-in-LDS, replicated gates, 1 cross-XCD exch/step ----
// Block (g=blk&7, j=blk>>3): units [8j,8j+8) for ALL 64 batches + logit cols [24*blk,+24).
__global__ __launch_bounds__(256) void dec_v(
    const float* __restrict__ Whh2, const float* __restrict__ E2p,
    const float* __restrict__ Wout, const float* __restrict__ bout,
    const float* __restrict__ hEnc, const float* __restrict__ cEnc,
    float* __restrict__ hG,        // [2][8][16384]
    u64* __restrict__ pInt,        // [8][32][64]
    u64* __restrict__ pX,          // [8][64]
    int* __restrict__ fA, int* __restrict__ fB, int* __restrict__ fG,
    float* __restrict__ out) {
    __shared__ __align__(16) float smem[16384 + 8192 + 6144 + 32 * 66 + 512];
    __shared__ u64 pm4[4][64];
    __shared__ int ssym[64];
    float* hs   = smem;                        // h[64][256] swizzled
    float* wsl  = smem + 16384;                // Whh2 slice [32][256] swizzled
    float* WoS  = smem + 16384 + 8192;         // Wout slice [24][256]
    float* gbuf = smem + 16384 + 8192 + 6144;  // [32][66]
    float* cls  = gbuf + 32 * 66;              // [8][64]
    const int tid = threadIdx.x;
    const int blk = blockIdx.x;
    const int g = blk & 7, j = blk >> 3;
    const int v0 = blk * 24;

    // Whh2 slice: rows rr=(uu=rr>>2? no: uu,gt) -> W row gt*256 + j*8 + uu; rr = uu*4+gt
    for (int rr = 0; rr < 32; ++rr) {
        int row = (rr & 3) * 256 + j * 8 + (rr >> 2);
        float w = Whh2[(size_t)row * 256 + tid];
        wsl[rr * 256 + (((tid >> 2) ^ (rr & 7)) << 2) + (tid & 3)] = w;
    }
    for (int i = tid; i < 24 * 256; i += 256)
        WoS[i] = Wout[(size_t)v0 * 256 + i];
    {   // stage h_enc (plain loads: kernel-boundary coherence)
        const float4* hf = (const float4*)hEnc;
        float4* hv = (float4*)hs;
        for (int i = tid; i < 4096; i += 256) {
            int b = i >> 6, s = i & 63;
            hv[(b << 6) + (s ^ (b & 7))] = hf[i];
        }
    }
    if (tid < 64) ssym[tid] = 1;
    {   // c state for units 8j+uu
        int uu = tid >> 6, b = tid & 63;
        cls[uu * 64 + b]       = cEnc[(size_t)b * 256 + j * 8 + uu];
        cls[(uu + 4) * 64 + b] = cEnc[(size_t)b * 256 + j * 8 + uu + 4];
    }
    __syncthreads();

    const float4* hq = (const float4*)hs;
    const float4* wq = (const float4*)wsl;
    const int w = tid >> 6, lane = tid & 63;
    const int r = (w & 1) * 16 + (lane >> 2);      // gate-row 0..31 (= uu*4+gt)
    const int bbase = (w >> 1) * 4 + (lane & 3);   // batch base, +8p
    const int rx = r & 7;

    for (int l = 0; l < L_DEC - 1; ++l) {
        // ---- gates: all 64 batches x 32 rows (replicated across groups) ----
        {
            float acc[8] = {0.f,0.f,0.f,0.f,0.f,0.f,0.f,0.f};
            for (int k4 = 0; k4 < 64; ++k4) {
                float4 w4 = wq[(r << 6) + (k4 ^ rx)];
#pragma unroll
                for (int p = 0; p < 8; ++p) {
                    float4 h4 = hq[((bbase + 8 * p) << 6) + (k4 ^ bbase)];
                    acc[p] = fmaf(h4.x, w4.x, fmaf(h4.y, w4.y,
                             fmaf(h4.z, w4.z, fmaf(h4.w, w4.w, acc[p]))));
                }
            }
#pragma unroll
            for (int p = 0; p < 8; ++p) gbuf[r * 66 + bbase + 8 * p] = acc[p];
        }
        __syncthreads();
        // ---- h' update for units 8j..8j+8, all batches ----
        float* hOut = hG + (size_t)(((l + 1) & 1) * 8 + g) * 16384;
        {
            int b = tid & 63;
            int row = ssym[b];
#pragma unroll
            for (int q = 0; q < 2; ++q) {
                int uu = (tid >> 6) + q * 4;
                float4 e4 = *(const float4*)(E2p + ((size_t)row << 10) + j * 32 + uu * 4);
                float gi = gbuf[(uu * 4 + 0) * 66 + b] + e4.x;
                float gf = gbuf[(uu * 4 + 1) * 66 + b] + e4.y;
                float gg = gbuf[(uu * 4 + 2) * 66 + b] + e4.z;
                float go = gbuf[(uu * 4 + 3) * 66 + b] + e4.w;
                float cn = sigf(gf) * cls[uu * 64 + b] + sigf(gi) * tanhf(gg);
                cls[uu * 64 + b] = cn;
                AT_STORE(&hOut[b * 256 + j * 8 + uu], sigf(go) * tanhf(cn));
            }
        }
        __syncthreads();
        if (tid == 0) AT_STORE(&fA[blk * DFS], l + 1);
        if (tid < 32) {
            const int* fp = &fA[(g + tid * 8) * DFS];
            while (AT_LOAD(fp) < l + 1) __builtin_amdgcn_s_sleep(1);
        }
        __syncthreads();
        asm volatile("" ::: "memory");
        {   // stage h_{l+1} from own group's copy (agent u64 loads bypass stale L2)
            const u64* src = (const u64*)hOut;
            float4* hv = (float4*)hs;
            for (int i = tid; i < 4096; i += 256) {
                int b = i >> 6, s = i & 63;
                u64 lo = AT_LOAD(&src[i * 2]);
                u64 hi = AT_LOAD(&src[i * 2 + 1]);
                float4 v;
                v.x = __uint_as_float((unsigned)lo); v.y = __uint_as_float((unsigned)(lo >> 32));
                v.z = __uint_as_float((unsigned)hi); v.w = __uint_as_float((unsigned)(hi >> 32));
                hv[(b << 6) + (s ^ (b & 7))] = v;
            }
        }
        __syncthreads();
        // ---- logits: 24 LDS cols; thread (cq=tid>>6, b=tid&63) -> 6 cols ----
        {
            int cq = tid >> 6, b = tid & 63;
            float acc6[6] = {0.f,0.f,0.f,0.f,0.f,0.f};
            for (int k4 = 0; k4 < 64; ++k4) {
                float4 h4 = hq[(b << 6) + (k4 ^ (b & 7))];
#pragma unroll
                for (int cc = 0; cc < 6; ++cc) {
                    float4 w4 = *(const float4*)&WoS[(cq * 6 + cc) * 256 + k4 * 4];
                    acc6[cc] = fmaf(h4.x, w4.x, fmaf(h4.y, w4.y,
                               fmaf(h4.z, w4.z, fmaf(h4.w, w4.w, acc6[cc]))));
                }
            }
            u64 best = 0ull;
            float* orow = out + (size_t)(b * L_DEC + l + 1) * V_SZ + v0 + cq * 6;
#pragma unroll
            for (int cc = 0; cc < 6; ++cc) {
                float lg = acc6[cc] + bout[v0 + cq * 6 + cc];
                orow[cc] = lg;
                u64 p = packmax(lg, v0 + cq * 6 + cc);
                if (p > best) best = p;
            }
            pm4[cq][b] = best;
        }
        __syncthreads();
        if (tid < 64) {
            u64 m = pm4[0][tid];
            if (pm4[1][tid] > m) m = pm4[1][tid];
            if (pm4[2][tid] > m) m = pm4[2][tid];
            if (pm4[3][tid] > m) m = pm4[3][tid];
            AT_STORE(&pInt[(g * 32 + j) * 64 + tid], m);
        }
        __syncthreads();
        if (tid == 0) AT_STORE(&fB[blk * DFS], l + 1);
        if (tid < 32) {
            const int* fp = &fB[(g + tid * 8) * DFS];
            while (AT_LOAD(fp) < l + 1) __builtin_amdgcn_s_sleep(1);
        }
        __syncthreads();
        asm volatile("" ::: "memory");
        {   // group-best: thread reduces its 8 entries (j-classes), same batch
            u64 m = 0ull;
#pragma unroll
            for (int k = 0; k < 8; ++k) {
                u64 p = AT_LOAD(&pInt[g * 2048 + tid + 256 * k]);
                if (p > m) m = p;
            }
            pm4[tid >> 6][tid & 63] = m;
        }
        __syncthreads();
        if (tid < 64) {
            u64 m = pm4[0][tid];
            if (pm4[1][tid] > m) m = pm4[1][tid];
            if (pm4[2][tid] > m) m = pm4[2][tid];
            if (pm4[3][tid] > m) m = pm4[3][tid];
            if (j == 0) AT_STORE(&pX[g * 64 + tid], m);
        }
        __syncthreads();
        if (j == 0 && tid == 0) AT_STORE(&fG[g * DFS], l + 1);
        if (tid < 8) {
            const int* fp = &fG[tid * DFS];
            while (AT_LOAD(fp) < l + 1) __builtin_amdgcn_s_sleep(1);
        }
        __syncthreads();
        asm volatile("" ::: "memory");
        if (tid < 64) {
            u64 m = 0ull;
#pragma unroll
            for (int gg = 0; gg < 8; ++gg) {
                u64 p = AT_LOAD(&pX[gg * 64 + tid]);
                if (p > m) m = p;
            }
            ssym[tid] = (int)(0x7FFFFFFFu - (unsigned)(m & 0xFFFFFFFFu));
        }
        __syncthreads();
        if (blk < 64 && tid == 0)
            out[SYMBASE + blk * L_DEC + l + 1] = (float)ssym[blk];
        __syncthreads();
    }
}

extern "C" void kernel_launch(void* const* d_in, const int* in_sizes, int n_in,
                              void* d_out, int out_size, void* d_ws, size_t ws_size,
                              hipStream_t stream) {
    const float* input = (const float*)d_in[0];
    // d_in[1] target_lengths: all == L_DEC, unused
    const float* embed = (const float*)d_in[2];
    const float* W_out = (const float*)d_in[3];
    const float* b_out = (const float*)d_in[4];
    const float* W_ih1 = (const float*)d_in[5];
    const float* W_hh1 = (const float*)d_in[6];
    const float* b_ih1 = (const float*)d_in[7];
    const float* b_hh1 = (const float*)d_in[8];
    const float* W_ih2 = (const float*)d_in[9];
    const float* W_hh2 = (const float*)d_in[10];
    const float* b_ih2 = (const float*)d_in[11];
    const float* b_hh2 = (const float*)d_in[12];
    float* out = (float*)d_out;

    float* ws = (float*)d_ws;
    float* X1p   = ws; ws += (size_t)T_IN * CH;            // 21.3M
    float* E2p   = ws; ws += (size_t)V_SZ * 1024;          // 25.2M
    float* hRotE = ws; ws += (size_t)T_IN * HSTR;          // 5.3M
    float* hG    = ws; ws += 2 * 8 * 16384;                // 1.0M
    float* cEnc  = ws; ws += 16384;
    float* bs1   = ws; ws += 1024;
    float* bs2   = ws; ws += 1024;
    u64* pInt    = (u64*)ws; ws += 2 * 8 * 32 * 64;
    u64* pX      = (u64*)ws; ws += 2 * 8 * 64;
    int* fA      = (int*)ws; ws += 256 * DFS;
    int* fB      = (int*)ws; ws += 256 * DFS;
    int* fG      = (int*)ws; ws += 8 * DFS;
    int* encFlag = (int*)ws; ws += 80 * 256 * FSTR;        // 5.2M
    unsigned* cnt = (unsigned*)ws; ws += 80 * 32;
    if (ws_size < (size_t)((float*)ws - (float*)d_ws) * 4) return;

    biasum<<<4, 256, 0, stream>>>(b_ih1, b_hh1, b_ih2, b_hh2, bs1, bs2);
    init0<<<256, 256, 0, stream>>>(encFlag, fA, fB, fG, cnt);
    e2gemm<<<dim3(8, 96), 256, 0, stream>>>(embed, W_ih2, bs2, E2p);
    dec0<<<24, 256, 0, stream>>>(embed, W_out, b_out, out);
    mega<<<NENC + NGEM, 256, 0, stream>>>(input, W_ih1, bs1, W_hh1,
                                          X1p, hRotE, cEnc, cnt, encFlag);
    dec_v<<<256, 256, 0, stream>>>(W_hh2, E2p, W_out, b_out,
                                   hRotE + (size_t)(T_IN - 1) * HSTR, cEnc,
                                   hG, pInt, pX, fA, fB, fG, out);
}

// Round 9
// 1338.069 us; speedup vs baseline: 2.9094x; 1.5073x over previous
//
#include <hip/hip_runtime.h>
#include <math.h>

#define B_SZ 64
#define T_IN 80
#define H_SZ 256
#define V_SZ 6144
#define L_DEC 30
#define SYMBASE (B_SZ * L_DEC * V_SZ)
#define CH 66560            // X1 t-chunk stride floats (64*1024 + guard)
#define HSTR 16640          // encoder h rotating stride floats
#define FSTR 16             // encoder flag stride (ints)
#define DFS 16              // decoder flag stride (ints)
#define NENC 256            // encoder blocks
#define NGEM 640            // X1 gemm blocks (80 t x 8 n)

typedef unsigned long long u64;
typedef unsigned short ushortt;
typedef __attribute__((ext_vector_type(8))) short bf16x8;
typedef __attribute__((ext_vector_type(4))) float f32x4;

#define AT_STORE(p, v) __hip_atomic_store((p), (v), __ATOMIC_RELAXED, __HIP_MEMORY_SCOPE_AGENT)
#define AT_LOAD(p)     __hip_atomic_load((p), __ATOMIC_RELAXED, __HIP_MEMORY_SCOPE_AGENT)

__device__ __forceinline__ float sigf(float x) { return 1.f / (1.f + expf(-x)); }

// monotone float->uint pack, first-index tie-break in low bits (never 0)
__device__ __forceinline__ u64 packmax(float v, int idx) {
    unsigned u = __float_as_uint(v);
    u = (u & 0x80000000u) ? ~u : (u | 0x80000000u);
    return ((u64)u << 32) | (unsigned)(0x7FFFFFFF - idx);
}

// gate-column permutation: n -> j*32 + uu*4 + gt  (u = n&255 = j*8+uu, gt = n>>8)
__device__ __forceinline__ int permcol(int n) {
    int u = n & 255, gt = n >> 8;
    return ((u >> 3) << 5) + ((u & 7) << 2) + gt;
}

// ---- fp32 -> bf16 hi/lo split (truncation; residual exact, lo keeps 8 more bits) ----
__device__ __forceinline__ unsigned pk2bf(float a, float b) {
    return (__float_as_uint(a) >> 16) | (__float_as_uint(b) & 0xffff0000u);
}
__device__ __forceinline__ float tr16(float f) {
    return __uint_as_float(__float_as_uint(f) & 0xffff0000u);
}
__device__ __forceinline__ void split8(const float* f, uint4& hi, uint4& lo) {
    hi.x = pk2bf(f[0], f[1]); hi.y = pk2bf(f[2], f[3]);
    hi.z = pk2bf(f[4], f[5]); hi.w = pk2bf(f[6], f[7]);
    float l0 = f[0] - tr16(f[0]), l1 = f[1] - tr16(f[1]);
    float l2 = f[2] - tr16(f[2]), l3 = f[3] - tr16(f[3]);
    float l4 = f[4] - tr16(f[4]), l5 = f[5] - tr16(f[5]);
    float l6 = f[6] - tr16(f[6]), l7 = f[7] - tr16(f[7]);
    lo.x = pk2bf(l0, l1); lo.y = pk2bf(l2, l3);
    lo.z = pk2bf(l4, l5); lo.w = pk2bf(l6, l7);
}

// ---------------- bias sums ----------------
__global__ void biasum(const float* a1, const float* b1, const float* a2, const float* b2,
                       float* o1, float* o2) {
    int i = blockIdx.x * 256 + threadIdx.x;
    if (i < 1024) { o1[i] = a1[i] + b1[i]; o2[i] = a2[i] + b2[i]; }
}

// ---------------- init: zero flags + chunk counters ----------------
__global__ void init0(int* encFlag, int* fA, int* fB, int* fG, unsigned* cnt) {
    int i = blockIdx.x * 256 + threadIdx.x;            // 65536 threads
    for (int k = i; k < 80 * 256 * FSTR; k += 65536) encFlag[k] = 0;
    if (i < 256 * DFS) { fA[i] = 0; fB[i] = 0; }
    if (i < 8 * DFS) fG[i] = 0;
    if (i < 80 * 32) cnt[i] = 0u;
}

// ---------------- pack W_ih1 [1024][4096] fp32 -> hi/lo bf16 (ushort) ----------------
__global__ __launch_bounds__(256) void packw1(const float* __restrict__ W,
                                              ushortt* __restrict__ Wh,
                                              ushortt* __restrict__ Wl) {
    int i = blockIdx.x * 256 + threadIdx.x;    // octet index, 524288 total
    float f[8];
    *(float4*)&f[0] = *(const float4*)(W + (size_t)i * 8);
    *(float4*)&f[4] = *(const float4*)(W + (size_t)i * 8 + 4);
    uint4 hi, lo;
    split8(f, hi, lo);
    ((uint4*)Wh)[i] = hi;
    ((uint4*)Wl)[i] = lo;
}

// ---------------- fp32 gemm body (kept for e2gemm): C[64][1024] = A@W^T + bias ----
__device__ __forceinline__ void gemm_body(
    const float* __restrict__ A, size_t astride, size_t aoff,
    const float* __restrict__ W, const float* __restrict__ bias,
    float* __restrict__ Cbase, int atomicC, int n0, int K, float* smem) {
    float* As = smem;              // [16][68]
    float* Bs = smem + 16 * 68;    // [16][132]
    const int tid = threadIdx.x;
    const int tx = tid & 15, ty = tid >> 4;
    const int a_m = tid >> 2, a_k = (tid & 3) * 4;
    const int b_n = tid >> 1, b_k = (tid & 1) * 8;

    float acc[4][8];
#pragma unroll
    for (int r = 0; r < 4; ++r)
#pragma unroll
        for (int c = 0; c < 8; ++c) acc[r][c] = 0.f;

    for (int k0 = 0; k0 < K; k0 += 16) {
        float4 av  = *(const float4*)(A + (size_t)a_m * astride + aoff + k0 + a_k);
        float4 bv0 = *(const float4*)(W + (size_t)(n0 + b_n) * K + k0 + b_k);
        float4 bv1 = *(const float4*)(W + (size_t)(n0 + b_n) * K + k0 + b_k + 4);
        __syncthreads();
        As[(a_k + 0) * 68 + a_m] = av.x; As[(a_k + 1) * 68 + a_m] = av.y;
        As[(a_k + 2) * 68 + a_m] = av.z; As[(a_k + 3) * 68 + a_m] = av.w;
        Bs[(b_k + 0) * 132 + b_n] = bv0.x; Bs[(b_k + 1) * 132 + b_n] = bv0.y;
        Bs[(b_k + 2) * 132 + b_n] = bv0.z; Bs[(b_k + 3) * 132 + b_n] = bv0.w;
        Bs[(b_k + 4) * 132 + b_n] = bv1.x; Bs[(b_k + 5) * 132 + b_n] = bv1.y;
        Bs[(b_k + 6) * 132 + b_n] = bv1.z; Bs[(b_k + 7) * 132 + b_n] = bv1.w;
        __syncthreads();
#pragma unroll
        for (int kk = 0; kk < 16; ++kk) {
            float4 a0 = *(const float4*)&As[kk * 68 + ty * 4];
            float4 b0 = *(const float4*)&Bs[kk * 132 + tx * 8];
            float4 b1 = *(const float4*)&Bs[kk * 132 + tx * 8 + 4];
            float ar[4] = {a0.x, a0.y, a0.z, a0.w};
            float br[8] = {b0.x, b0.y, b0.z, b0.w, b1.x, b1.y, b1.z, b1.w};
#pragma unroll
            for (int r = 0; r < 4; ++r)
#pragma unroll
                for (int c = 0; c < 8; ++c)
                    acc[r][c] = fmaf(ar[r], br[c], acc[r][c]);
        }
    }
#pragma unroll
    for (int r = 0; r < 4; ++r) {
        int row = ty * 4 + r;
#pragma unroll
        for (int c = 0; c < 8; ++c) {
            int n = n0 + tx * 8 + c;
            float v = acc[r][c] + bias[n];
            float* dst = Cbase + (size_t)row * 1024 + permcol(n);
            if (atomicC) AT_STORE(dst, v);
            else *dst = v;
        }
    }
}

// ---------------- E2p gemm ----------------
__global__ __launch_bounds__(256) void e2gemm(const float* __restrict__ embed,
                                              const float* __restrict__ W_ih2,
                                              const float* __restrict__ bs2,
                                              float* __restrict__ E2p) {
    __shared__ __align__(16) float smem[16 * 68 + 16 * 132];
    int my = blockIdx.y, nx = blockIdx.x;
    gemm_body(embed + (size_t)my * 64 * 256, 256, 0, W_ih2, bs2,
              E2p + (size_t)my * 64 * 1024, 0, nx * 128, 256, smem);
}

// ---------------- step-0 outputs ----------------
__global__ __launch_bounds__(256) void dec0(const float* __restrict__ embed,
                                            const float* __restrict__ Wout,
                                            const float* __restrict__ bout,
                                            float* __restrict__ out) {
    __shared__ float es[256];
    int tid = threadIdx.x;
    int v = blockIdx.x * 256 + tid;
    es[tid] = embed[256 + tid];  // row SOS=1
    __syncthreads();
    float a = 0.f, a2 = 0.f;
    const float* wr = Wout + (size_t)v * 256;
    for (int k = 0; k < 256; k += 8) {
        float4 w0 = *(const float4*)(wr + k);
        float4 w1 = *(const float4*)(wr + k + 4);
        a  = fmaf(es[k+0],w0.x,fmaf(es[k+1],w0.y,fmaf(es[k+2],w0.z,fmaf(es[k+3],w0.w,a))));
        a2 = fmaf(es[k+4],w1.x,fmaf(es[k+5],w1.y,fmaf(es[k+6],w1.z,fmaf(es[k+7],w1.w,a2))));
    }
    float lg = a + a2 + bout[v];
    for (int b = 0; b < B_SZ; ++b) out[(size_t)b * L_DEC * V_SZ + v] = lg;
    if (blockIdx.x == 0 && tid < B_SZ) out[SYMBASE + tid * L_DEC] = 1.0f;
}

// ---------------- mega: encoder (256 blocks) ∥ split-bf16 MFMA X1 gemm (640) ----
// GEMM block (t, nx): C[64 batches][128 cols] for chunk t, cols nx*128..+128, K=4096.
__global__ __launch_bounds__(256) void mega(
    const float* __restrict__ input,
    const ushortt* __restrict__ wH, const ushortt* __restrict__ wL,
    const float* __restrict__ bs1, const float* __restrict__ Whh1,
    float* __restrict__ X1p, float* __restrict__ hRotE, float* __restrict__ cEnc,
    unsigned* __restrict__ cnt, int* __restrict__ encFlag) {
    __shared__ __align__(16) float smem[10568];
    const int tid = threadIdx.x;
    const int blk = blockIdx.x;

    if (blk >= NENC) {   // ================= MFMA X1 gemm =================
        const int q = blk - NENC, t = q >> 3, nx = q & 7;
        const int n0 = nx * 128;
        ushortt* lds = (ushortt*)smem;
        ushortt* AhL = lds;            // [64][40]  (80B rows: bank-friendly)
        ushortt* AlL = lds + 2560;
        ushortt* BhL = lds + 5120;     // [128][40]
        ushortt* BlL = lds + 10240;

        // staging: A one 16B unit (hi+lo derived), W two 16B units per array
        const int ar = tid >> 2, as = tid & 3;
        const float*  aSrc   = input + ((size_t)(ar * T_IN + t)) * 4096 + as * 8;
        const int     awOff  = ar * 40 + as * 8;
        const int wrow = tid >> 2, wseg = tid & 3;
        const ushortt* whSrc0 = wH + ((size_t)(n0 + wrow)) * 4096 + wseg * 8;
        const ushortt* wlSrc0 = wL + ((size_t)(n0 + wrow)) * 4096 + wseg * 8;
        const ushortt* whSrc1 = whSrc0 + (size_t)64 * 4096;
        const ushortt* wlSrc1 = wlSrc0 + (size_t)64 * 4096;
        const int wwOff0 = wrow * 40 + wseg * 8;
        const int wwOff1 = (wrow + 64) * 40 + wseg * 8;

        // wave tiling: 4 waves in 2x2; wave tile 32m x 64n; frags 2m x 4n
        const int w = tid >> 6, l = tid & 63;
        const int wm = w >> 1, wn = w & 1;
        const int fr = l & 15, fs = l >> 4;
        const int aRd0 = (wm * 32 + fr) * 40 + fs * 8;
        const int aRd1 = (wm * 32 + 16 + fr) * 40 + fs * 8;
        int bRd[4];
#pragma unroll
        for (int j = 0; j < 4; ++j) bRd[j] = (wn * 64 + j * 16 + fr) * 40 + fs * 8;

        f32x4 acc0[4], acc1[4];
#pragma unroll
        for (int j = 0; j < 4; ++j) { acc0[j] = (f32x4)0.f; acc1[j] = (f32x4)0.f; }

        float af[8];
        uint4 w0h, w0l, w1h, w1l;
        // prologue: stage 0 loads
        *(float4*)&af[0] = *(const float4*)(aSrc);
        *(float4*)&af[4] = *(const float4*)(aSrc + 4);
        w0h = *(const uint4*)(whSrc0); w0l = *(const uint4*)(wlSrc0);
        w1h = *(const uint4*)(whSrc1); w1l = *(const uint4*)(wlSrc1);

        for (int k0 = 0; k0 < 4096; k0 += 32) {
            uint4 ahi, alo;
            split8(af, ahi, alo);
            asm volatile("s_waitcnt lgkmcnt(0)" ::: "memory");
            __builtin_amdgcn_s_barrier();          // prior readers done
            __builtin_amdgcn_sched_barrier(0);
            *(uint4*)&AhL[awOff] = ahi;
            *(uint4*)&AlL[awOff] = alo;
            *(uint4*)&BhL[wwOff0] = w0h;
            *(uint4*)&BlL[wwOff0] = w0l;
            *(uint4*)&BhL[wwOff1] = w1h;
            *(uint4*)&BlL[wwOff1] = w1l;
            if (k0 + 32 < 4096) {                  // prefetch next stage (stays in flight)
                *(float4*)&af[0] = *(const float4*)(aSrc + k0 + 32);
                *(float4*)&af[4] = *(const float4*)(aSrc + k0 + 36);
                w0h = *(const uint4*)(whSrc0 + k0 + 32);
                w0l = *(const uint4*)(wlSrc0 + k0 + 32);
                w1h = *(const uint4*)(whSrc1 + k0 + 32);
                w1l = *(const uint4*)(wlSrc1 + k0 + 32);
            }
            asm volatile("s_waitcnt lgkmcnt(0)" ::: "memory");
            __builtin_amdgcn_s_barrier();          // LDS writes visible (vmcnt NOT drained)
            __builtin_amdgcn_sched_barrier(0);

            bf16x8 a0h = *(const bf16x8*)&AhL[aRd0];
            bf16x8 a0l = *(const bf16x8*)&AlL[aRd0];
            bf16x8 a1h = *(const bf16x8*)&AhL[aRd1];
            bf16x8 a1l = *(const bf16x8*)&AlL[aRd1];
#pragma unroll
            for (int j = 0; j < 4; ++j) {
                bf16x8 bh = *(const bf16x8*)&BhL[bRd[j]];
                bf16x8 bl = *(const bf16x8*)&BlL[bRd[j]];
                acc0[j] = __builtin_amdgcn_mfma_f32_16x16x32_bf16(a0h, bh, acc0[j], 0, 0, 0);
                acc0[j] = __builtin_amdgcn_mfma_f32_16x16x32_bf16(a0h, bl, acc0[j], 0, 0, 0);
                acc0[j] = __builtin_amdgcn_mfma_f32_16x16x32_bf16(a0l, bh, acc0[j], 0, 0, 0);
                acc1[j] = __builtin_amdgcn_mfma_f32_16x16x32_bf16(a1h, bh, acc1[j], 0, 0, 0);
                acc1[j] = __builtin_amdgcn_mfma_f32_16x16x32_bf16(a1h, bl, acc1[j], 0, 0, 0);
                acc1[j] = __builtin_amdgcn_mfma_f32_16x16x32_bf16(a1l, bh, acc1[j], 0, 0, 0);
            }
        }

        // epilogue: bias + gate-permute + agent-scope store into chunk t
        float* Xc = X1p + (size_t)t * CH;
#pragma unroll
        for (int j = 0; j < 4; ++j) {
            int n = n0 + wn * 64 + j * 16 + fr;
            float bv = bs1[n];
            int pc = permcol(n);
            int m0 = wm * 32 + fs * 4;
#pragma unroll
            for (int r = 0; r < 4; ++r) {
                AT_STORE(&Xc[(size_t)(m0 + r) * 1024 + pc], acc0[j][r] + bv);
                AT_STORE(&Xc[(size_t)(m0 + 16 + r) * 1024 + pc], acc1[j][r] + bv);
            }
        }
        __syncthreads();   // drains vmcnt: all stores visible before flag
        if (tid == 0)
            __hip_atomic_fetch_add(&cnt[t * 32], 1u,
                                   __ATOMIC_RELAXED, __HIP_MEMORY_SCOPE_AGENT);
        return;
    }

    // ================= encoder (unchanged) =================
    const int g = blk & 7, j = blk >> 3;
    float* wsl  = smem;            // [32][256] swizzled
    float* hgrp = smem + 8192;     // [8][256]
    float* gbuf = smem + 10240;    // [8][33]
    float* cls  = smem + 10504;    // [64]
    float4* wsl4  = (float4*)wsl;
    float4* hgrp4 = (float4*)hgrp;

    for (int rr = 0; rr < 32; ++rr) {
        int row = (rr & 3) * 256 + j * 8 + (rr >> 2);
        float w = Whh1[(size_t)row * 256 + tid];
        wsl[rr * 256 + (((tid >> 2) ^ (rr & 15)) << 2) + (tid & 3)] = w;
    }
    for (int i = tid; i < 2048; i += 256) hgrp[i] = 0.f;
    if (tid < 64) cls[tid] = 0.f;
    __syncthreads();

    const int b = tid >> 5, r = tid & 31, rx = r & 15;
    for (int t = 0; t < T_IN; ++t) {
        if (tid == 0) {
            while (AT_LOAD(&cnt[t * 32]) < 8u) __builtin_amdgcn_s_sleep(4);
        }
        __syncthreads();
        asm volatile("" ::: "memory");
        float acc = X1p[(size_t)t * CH + ((size_t)(g * 8 + b) << 10) + j * 32 + r];
        const float4* hb4 = hgrp4 + (b << 6);
#pragma unroll 8
        for (int kq = 0; kq < 64; ++kq) {
            float4 w4 = wsl4[(r << 6) + (kq ^ rx)];
            float4 h4 = hb4[kq];
            acc = fmaf(h4.x, w4.x, fmaf(h4.y, w4.y,
                  fmaf(h4.z, w4.z, fmaf(h4.w, w4.w, acc))));
        }
        gbuf[b * 33 + r] = acc;
        __syncthreads();
        float* hstep = hRotE + (size_t)t * HSTR;
        if (tid < 64) {
            int bb = tid >> 3, uu = tid & 7;
            float gi = gbuf[bb * 33 + uu * 4 + 0];
            float gf = gbuf[bb * 33 + uu * 4 + 1];
            float gg = gbuf[bb * 33 + uu * 4 + 2];
            float go = gbuf[bb * 33 + uu * 4 + 3];
            float cn = sigf(gf) * cls[tid] + sigf(gi) * tanhf(gg);
            cls[tid] = cn;
            float hn = sigf(go) * tanhf(cn);
            AT_STORE(&hstep[((size_t)(g * 8 + bb) << 8) + j * 8 + uu], hn);
            if (t == T_IN - 1) cEnc[((g * 8 + bb) << 8) + j * 8 + uu] = cn;
        }
        __syncthreads();
        if (tid == 0) AT_STORE(&encFlag[(t * 256 + blk) * FSTR], t + 1);
        if (tid < 32) {
            const int* fp = &encFlag[(t * 256 + g + tid * 8) * FSTR];
            while (AT_LOAD(fp) != t + 1) __builtin_amdgcn_s_sleep(1);
        }
        __syncthreads();
        asm volatile("" ::: "memory");
        const float4* hsrc = (const float4*)hstep + (size_t)(g * 8) * 64;
        for (int i = tid; i < 512; i += 256) hgrp4[i] = hsrc[i];
        __syncthreads();
    }
}

// ---------------- decoder (unchanged from round 8) ----------------
__global__ __launch_bounds__(256) void dec_v(
    const float* __restrict__ Whh2, const float* __restrict__ E2p,
    const float* __restrict__ Wout, const float* __restrict__ bout,
    const float* __restrict__ hEnc, const float* __restrict__ cEnc,
    float* __restrict__ hG,        // [2][8][16384]
    u64* __restrict__ pInt,        // [8][32][64]
    u64* __restrict__ pX,          // [8][64]
    int* __restrict__ fA, int* __restrict__ fB, int* __restrict__ fG,
    float* __restrict__ out) {
    __shared__ __align__(16) float smem[16384 + 8192 + 6144 + 32 * 66 + 512];
    __shared__ u64 pm4[4][64];
    __shared__ int ssym[64];
    float* hs   = smem;                        // h[64][256] swizzled
    float* wsl  = smem + 16384;                // Whh2 slice [32][256] swizzled
    float* WoS  = smem + 16384 + 8192;         // Wout slice [24][256]
    float* gbuf = smem + 16384 + 8192 + 6144;  // [32][66]
    float* cls  = gbuf + 32 * 66;              // [8][64]
    const int tid = threadIdx.x;
    const int blk = blockIdx.x;
    const int g = blk & 7, j = blk >> 3;
    const int v0 = blk * 24;

    for (int rr = 0; rr < 32; ++rr) {
        int row = (rr & 3) * 256 + j * 8 + (rr >> 2);
        float w = Whh2[(size_t)row * 256 + tid];
        wsl[rr * 256 + (((tid >> 2) ^ (rr & 7)) << 2) + (tid & 3)] = w;
    }
    for (int i = tid; i < 24 * 256; i += 256)
        WoS[i] = Wout[(size_t)v0 * 256 + i];
    {
        const float4* hf = (const float4*)hEnc;
        float4* hv = (float4*)hs;
        for (int i = tid; i < 4096; i += 256) {
            int b = i >> 6, s = i & 63;
            hv[(b << 6) + (s ^ (b & 7))] = hf[i];
        }
    }
    if (tid < 64) ssym[tid] = 1;
    {
        int uu = tid >> 6, b = tid & 63;
        cls[uu * 64 + b]       = cEnc[(size_t)b * 256 + j * 8 + uu];
        cls[(uu + 4) * 64 + b] = cEnc[(size_t)b * 256 + j * 8 + uu + 4];
    }
    __syncthreads();

    const float4* hq = (const float4*)hs;
    const float4* wq = (const float4*)wsl;
    const int w = tid >> 6, lane = tid & 63;
    const int r = (w & 1) * 16 + (lane >> 2);
    const int bbase = (w >> 1) * 4 + (lane & 3);
    const int rx = r & 7;

    for (int l = 0; l < L_DEC - 1; ++l) {
        {
            float acc[8] = {0.f,0.f,0.f,0.f,0.f,0.f,0.f,0.f};
            for (int k4 = 0; k4 < 64; ++k4) {
                float4 w4 = wq[(r << 6) + (k4 ^ rx)];
#pragma unroll
                for (int p = 0; p < 8; ++p) {
                    float4 h4 = hq[((bbase + 8 * p) << 6) + (k4 ^ bbase)];
                    acc[p] = fmaf(h4.x, w4.x, fmaf(h4.y, w4.y,
                             fmaf(h4.z, w4.z, fmaf(h4.w, w4.w, acc[p]))));
                }
            }
#pragma unroll
            for (int p = 0; p < 8; ++p) gbuf[r * 66 + bbase + 8 * p] = acc[p];
        }
        __syncthreads();
        float* hOut = hG + (size_t)(((l + 1) & 1) * 8 + g) * 16384;
        {
            int b = tid & 63;
            int row = ssym[b];
#pragma unroll
            for (int q = 0; q < 2; ++q) {
                int uu = (tid >> 6) + q * 4;
                float4 e4 = *(const float4*)(E2p + ((size_t)row << 10) + j * 32 + uu * 4);
                float gi = gbuf[(uu * 4 + 0) * 66 + b] + e4.x;
                float gf = gbuf[(uu * 4 + 1) * 66 + b] + e4.y;
                float gg = gbuf[(uu * 4 + 2) * 66 + b] + e4.z;
                float go = gbuf[(uu * 4 + 3) * 66 + b] + e4.w;
                float cn = sigf(gf) * cls[uu * 64 + b] + sigf(gi) * tanhf(gg);
                cls[uu * 64 + b] = cn;
                AT_STORE(&hOut[b * 256 + j * 8 + uu], sigf(go) * tanhf(cn));
            }
        }
        __syncthreads();
        if (tid == 0) AT_STORE(&fA[blk * DFS], l + 1);
        if (tid < 32) {
            const int* fp = &fA[(g + tid * 8) * DFS];
            while (AT_LOAD(fp) < l + 1) __builtin_amdgcn_s_sleep(1);
        }
        __syncthreads();
        asm volatile("" ::: "memory");
        {
            const u64* src = (const u64*)hOut;
            float4* hv = (float4*)hs;
            for (int i = tid; i < 4096; i += 256) {
                int b = i >> 6, s = i & 63;
                u64 lo = AT_LOAD(&src[i * 2]);
                u64 hi = AT_LOAD(&src[i * 2 + 1]);
                float4 v;
                v.x = __uint_as_float((unsigned)lo); v.y = __uint_as_float((unsigned)(lo >> 32));
                v.z = __uint_as_float((unsigned)hi); v.w = __uint_as_float((unsigned)(hi >> 32));
                hv[(b << 6) + (s ^ (b & 7))] = v;
            }
        }
        __syncthreads();
        {
            int cq = tid >> 6, b = tid & 63;
            float acc6[6] = {0.f,0.f,0.f,0.f,0.f,0.f};
            for (int k4 = 0; k4 < 64; ++k4) {
                float4 h4 = hq[(b << 6) + (k4 ^ (b & 7))];
#pragma unroll
                for (int cc = 0; cc < 6; ++cc) {
                    float4 w4 = *(const float4*)&WoS[(cq * 6 + cc) * 256 + k4 * 4];
                    acc6[cc] = fmaf(h4.x, w4.x, fmaf(h4.y, w4.y,
                               fmaf(h4.z, w4.z, fmaf(h4.w, w4.w, acc6[cc]))));
                }
            }
            u64 best = 0ull;
            float* orow = out + (size_t)(b * L_DEC + l + 1) * V_SZ + v0 + cq * 6;
#pragma unroll
            for (int cc = 0; cc < 6; ++cc) {
                float lg = acc6[cc] + bout[v0 + cq * 6 + cc];
                orow[cc] = lg;
                u64 p = packmax(lg, v0 + cq * 6 + cc);
                if (p > best) best = p;
            }
            pm4[cq][b] = best;
        }
        __syncthreads();
        if (tid < 64) {
            u64 m = pm4[0][tid];
            if (pm4[1][tid] > m) m = pm4[1][tid];
            if (pm4[2][tid] > m) m = pm4[2][tid];
            if (pm4[3][tid] > m) m = pm4[3][tid];
            AT_STORE(&pInt[(g * 32 + j) * 64 + tid], m);
        }
        __syncthreads();
        if (tid == 0) AT_STORE(&fB[blk * DFS], l + 1);
        if (tid < 32) {
            const int* fp = &fB[(g + tid * 8) * DFS];
            while (AT_LOAD(fp) < l + 1) __builtin_amdgcn_s_sleep(1);
        }
        __syncthreads();
        asm volatile("" ::: "memory");
        {
            u64 m = 0ull;
#pragma unroll
            for (int k = 0; k < 8; ++k) {
                u64 p = AT_LOAD(&pInt[g * 2048 + tid + 256 * k]);
                if (p > m) m = p;
            }
            pm4[tid >> 6][tid & 63] = m;
        }
        __syncthreads();
        if (tid < 64) {
            u64 m = pm4[0][tid];
            if (pm4[1][tid] > m) m = pm4[1][tid];
            if (pm4[2][tid] > m) m = pm4[2][tid];
            if (pm4[3][tid] > m) m = pm4[3][tid];
            if (j == 0) AT_STORE(&pX[g * 64 + tid], m);
        }
        __syncthreads();
        if (j == 0 && tid == 0) AT_STORE(&fG[g * DFS], l + 1);
        if (tid < 8) {
            const int* fp = &fG[tid * DFS];
            while (AT_LOAD(fp) < l + 1) __builtin_amdgcn_s_sleep(1);
        }
        __syncthreads();
        asm volatile("" ::: "memory");
        if (tid < 64) {
            u64 m = 0ull;
#pragma unroll
            for (int gg = 0; gg < 8; ++gg) {
                u64 p = AT_LOAD(&pX[gg * 64 + tid]);
                if (p > m) m = p;
            }
            ssym[tid] = (int)(0x7FFFFFFFu - (unsigned)(m & 0xFFFFFFFFu));
        }
        __syncthreads();
        if (blk < 64 && tid == 0)
            out[SYMBASE + blk * L_DEC + l + 1] = (float)ssym[blk];
        __syncthreads();
    }
}

extern "C" void kernel_launch(void* const* d_in, const int* in_sizes, int n_in,
                              void* d_out, int out_size, void* d_ws, size_t ws_size,
                              hipStream_t stream) {
    const float* input = (const float*)d_in[0];
    // d_in[1] target_lengths: all == L_DEC, unused
    const float* embed = (const float*)d_in[2];
    const float* W_out = (const float*)d_in[3];
    const float* b_out = (const float*)d_in[4];
    const float* W_ih1 = (const float*)d_in[5];
    const float* W_hh1 = (const float*)d_in[6];
    const float* b_ih1 = (const float*)d_in[7];
    const float* b_hh1 = (const float*)d_in[8];
    const float* W_ih2 = (const float*)d_in[9];
    const float* W_hh2 = (const float*)d_in[10];
    const float* b_ih2 = (const float*)d_in[11];
    const float* b_hh2 = (const float*)d_in[12];
    float* out = (float*)d_out;

    float* ws = (float*)d_ws;
    float* X1p   = ws; ws += (size_t)T_IN * CH;            // 21.3M
    float* E2p   = ws; ws += (size_t)V_SZ * 1024;          // 25.2M
    float* hRotE = ws; ws += (size_t)T_IN * HSTR;          // 5.3M
    float* hG    = ws; ws += 2 * 8 * 16384;                // 1.0M
    float* cEnc  = ws; ws += 16384;
    float* bs1   = ws; ws += 1024;
    float* bs2   = ws; ws += 1024;
    ushortt* wH  = (ushortt*)ws; ws += (size_t)1024 * 4096 / 2;   // 8.4M
    ushortt* wL  = (ushortt*)ws; ws += (size_t)1024 * 4096 / 2;   // 8.4M
    u64* pInt    = (u64*)ws; ws += 2 * 8 * 32 * 64;
    u64* pX      = (u64*)ws; ws += 2 * 8 * 64;
    int* fA      = (int*)ws; ws += 256 * DFS;
    int* fB      = (int*)ws; ws += 256 * DFS;
    int* fG      = (int*)ws; ws += 8 * DFS;
    int* encFlag = (int*)ws; ws += 80 * 256 * FSTR;        // 5.2M
    unsigned* cnt = (unsigned*)ws; ws += 80 * 32;
    if (ws_size < (size_t)((float*)ws - (float*)d_ws) * 4) return;

    biasum<<<4, 256, 0, stream>>>(b_ih1, b_hh1, b_ih2, b_hh2, bs1, bs2);
    init0<<<256, 256, 0, stream>>>(encFlag, fA, fB, fG, cnt);
    packw1<<<2048, 256, 0, stream>>>(W_ih1, wH, wL);
    e2gemm<<<dim3(8, 96), 256, 0, stream>>>(embed, W_ih2, bs2, E2p);
    dec0<<<24, 256, 0, stream>>>(embed, W_out, b_out, out);
    mega<<<NENC + NGEM, 256, 0, stream>>>(input, wH, wL, bs1, W_hh1,
                                          X1p, hRotE, cEnc, cnt, encFlag);
    dec_v<<<256, 256, 0, stream>>>(W_hh2, E2p, W_out, b_out,
                                   hRotE + (size_t)(T_IN - 1) * HSTR, cEnc,
                                   hG, pInt, pX, fA, fB, fG, out);
}